// Round 1
// baseline (3674.875 us; speedup 1.0000x reference)
//
#include <hip/hip_runtime.h>
#include <math.h>

// Problem constants (from reference)
constexpr int T = 1024;
constexpr int H = 2048;
constexpr int I = 1024;
constexpr int E = 16;
constexpr int K = 2;
constexpr int L = 4;
constexpr int R = 16;
constexpr int P = T * K;   // 2048 (token, k) pairs

// ---------------------------------------------------------------------------
// Workspace layout (bytes):
//   [0        ) expert_off  : (E+1) ints
//   [128      ) pair_t      : P ints   (token index, sorted by expert)
//   [128+4P   ) pair_e      : P ints   (expert id per sorted pair)
//   [128+8P   ) pair_w      : P floats (routing weight per sorted pair)
//   [32768    ) act         : P*I floats (silu(gate)*up, sorted-pair order)
// total ~8.4 MB
// ---------------------------------------------------------------------------

__global__ __launch_bounds__(256) void route_kernel(
    const int* __restrict__ topk_ids, const float* __restrict__ topk_w,
    int* __restrict__ eoff, int* __restrict__ pair_t,
    float* __restrict__ pair_w, int* __restrict__ pair_e) {
  __shared__ int cnt[E];
  __shared__ int off[E + 1];
  __shared__ int cur[E];
  const int tid = threadIdx.x;
  if (tid < E) cnt[tid] = 0;
  __syncthreads();
  for (int p = tid; p < P; p += blockDim.x) {
    atomicAdd(&cnt[topk_ids[p]], 1);
  }
  __syncthreads();
  if (tid == 0) {
    off[0] = 0;
    for (int e = 0; e < E; ++e) off[e + 1] = off[e] + cnt[e];
  }
  __syncthreads();
  if (tid < E) cur[tid] = off[tid];
  if (tid <= E) eoff[tid] = off[tid];
  __syncthreads();
  for (int p = tid; p < P; p += blockDim.x) {
    const int e = topk_ids[p];
    const int pos = atomicAdd(&cur[e], 1);
    pair_t[pos] = p / K;
    pair_w[pos] = topk_w[p];
    pair_e[pos] = e;
  }
}

// GEMM1: act[p, i] = silu(x[t]·w1[e, i, :]) * (x[t]·w1[e, I+i, :])
// tiles: BM=64 pairs x BN=64 i-values, BK=16 over H
__global__ __launch_bounds__(256) void gemm1_silu(
    const float* __restrict__ x, const float* __restrict__ w1,
    const int* __restrict__ eoff, const int* __restrict__ pair_t,
    float* __restrict__ act) {
  const int e = blockIdx.z;
  const int beg = eoff[e];
  const int cnt = eoff[e + 1] - beg;
  const int m0 = blockIdx.x * 64;
  if (m0 >= cnt) return;
  const int i0 = blockIdx.y * 64;

  __shared__ float xs[16][68];
  __shared__ float gs[16][68];
  __shared__ float us[16][68];

  const int tid = threadIdx.x;
  const int lm = tid >> 2;          // 0..63 (row within tile)
  const int lk = (tid & 3) << 2;    // 0,4,8,12 (k offset)
  const int tr4 = (tid >> 4) << 2;  // m sub-tile offset
  const int tc4 = (tid & 15) << 2;  // n sub-tile offset

  const int tok = (m0 + lm < cnt) ? pair_t[beg + m0 + lm] : -1;
  const float* xrow = x + (size_t)(tok < 0 ? 0 : tok) * H;
  const float* grow = w1 + ((size_t)e * (2 * I) + (i0 + lm)) * H;
  const float* urow = grow + (size_t)I * H;

  float ag[4][4] = {{0.f}};
  float au[4][4] = {{0.f}};

  for (int kk = 0; kk < H; kk += 16) {
    float4 xv = make_float4(0.f, 0.f, 0.f, 0.f);
    if (tok >= 0) xv = *reinterpret_cast<const float4*>(xrow + kk + lk);
    const float4 gv = *reinterpret_cast<const float4*>(grow + kk + lk);
    const float4 uv = *reinterpret_cast<const float4*>(urow + kk + lk);
    __syncthreads();
    xs[lk + 0][lm] = xv.x; xs[lk + 1][lm] = xv.y; xs[lk + 2][lm] = xv.z; xs[lk + 3][lm] = xv.w;
    gs[lk + 0][lm] = gv.x; gs[lk + 1][lm] = gv.y; gs[lk + 2][lm] = gv.z; gs[lk + 3][lm] = gv.w;
    us[lk + 0][lm] = uv.x; us[lk + 1][lm] = uv.y; us[lk + 2][lm] = uv.z; us[lk + 3][lm] = uv.w;
    __syncthreads();
#pragma unroll
    for (int k = 0; k < 16; ++k) {
      float a[4], g[4], u[4];
#pragma unroll
      for (int j = 0; j < 4; ++j) {
        a[j] = xs[k][tr4 + j];
        g[j] = gs[k][tc4 + j];
        u[j] = us[k][tc4 + j];
      }
#pragma unroll
      for (int mi = 0; mi < 4; ++mi)
#pragma unroll
        for (int nj = 0; nj < 4; ++nj) {
          ag[mi][nj] += a[mi] * g[nj];
          au[mi][nj] += a[mi] * u[nj];
        }
    }
  }

#pragma unroll
  for (int mi = 0; mi < 4; ++mi) {
    const int m = m0 + tr4 + mi;
    if (m >= cnt) continue;
    float vals[4];
#pragma unroll
    for (int nj = 0; nj < 4; ++nj) {
      const float g = ag[mi][nj];
      const float s = g / (1.f + __expf(-g));   // silu
      vals[nj] = s * au[mi][nj];
    }
    float* dst = act + (size_t)(beg + m) * I + i0 + tc4;
    *reinterpret_cast<float4*>(dst) = make_float4(vals[0], vals[1], vals[2], vals[3]);
  }
}

// GEMM2: out[t, h] += w_p * (act[p, :]·w2[e, h, :])
// tiles: BM=64 pairs x BN=64 h-values, BK=16 over I
__global__ __launch_bounds__(256) void gemm2_base(
    const float* __restrict__ act, const float* __restrict__ w2,
    const int* __restrict__ eoff, const int* __restrict__ pair_t,
    const float* __restrict__ pair_w, float* __restrict__ out) {
  const int e = blockIdx.z;
  const int beg = eoff[e];
  const int cnt = eoff[e + 1] - beg;
  const int m0 = blockIdx.x * 64;
  if (m0 >= cnt) return;
  const int h0 = blockIdx.y * 64;

  __shared__ float as[16][68];
  __shared__ float bs[16][68];

  const int tid = threadIdx.x;
  const int lm = tid >> 2;
  const int lk = (tid & 3) << 2;
  const int tr4 = (tid >> 4) << 2;
  const int tc4 = (tid & 15) << 2;

  const bool mval = (m0 + lm) < cnt;
  const float* arow = act + (size_t)(beg + (mval ? m0 + lm : 0)) * I;
  const float* wrow = w2 + ((size_t)e * H + (h0 + lm)) * I;

  float acc[4][4] = {{0.f}};

  for (int kk = 0; kk < I; kk += 16) {
    float4 av = make_float4(0.f, 0.f, 0.f, 0.f);
    if (mval) av = *reinterpret_cast<const float4*>(arow + kk + lk);
    const float4 wv = *reinterpret_cast<const float4*>(wrow + kk + lk);
    __syncthreads();
    as[lk + 0][lm] = av.x; as[lk + 1][lm] = av.y; as[lk + 2][lm] = av.z; as[lk + 3][lm] = av.w;
    bs[lk + 0][lm] = wv.x; bs[lk + 1][lm] = wv.y; bs[lk + 2][lm] = wv.z; bs[lk + 3][lm] = wv.w;
    __syncthreads();
#pragma unroll
    for (int k = 0; k < 16; ++k) {
      float a[4], b[4];
#pragma unroll
      for (int j = 0; j < 4; ++j) {
        a[j] = as[k][tr4 + j];
        b[j] = bs[k][tc4 + j];
      }
#pragma unroll
      for (int mi = 0; mi < 4; ++mi)
#pragma unroll
        for (int nj = 0; nj < 4; ++nj) acc[mi][nj] += a[mi] * b[nj];
    }
  }

#pragma unroll
  for (int mi = 0; mi < 4; ++mi) {
    const int m = m0 + tr4 + mi;
    if (m >= cnt) continue;
    const int t = pair_t[beg + m];
    const float w = pair_w[beg + m];
    float* orow = out + (size_t)t * H + h0 + tc4;
#pragma unroll
    for (int nj = 0; nj < 4; ++nj) atomicAdd(orow + nj, w * acc[mi][nj]);
  }
}

// LoRA: per pair p: a_r = scal * (x[t]·A[l,e,r,:]) for r<rank; out[t] += a·B[l,e,:,:]^T
__global__ __launch_bounds__(256) void lora_kernel(
    const float* __restrict__ x, const float* __restrict__ lora_a,
    const float* __restrict__ lora_b, const int* __restrict__ lora_idx,
    const int* __restrict__ lora_ranks, const float* __restrict__ scalings,
    const int* __restrict__ pair_t, const int* __restrict__ pair_e,
    float* __restrict__ out) {
  const int p = blockIdx.x;
  const int t = pair_t[p];
  const int e = pair_e[p];
  const int l = lora_idx[t];
  if (l < 0) return;
  int rank = lora_ranks[l];
  if (rank < 1) rank = 1;
  const float sc = scalings[l];

  __shared__ float xrow[H];
  __shared__ float a_sh[R];

  const int tid = threadIdx.x;
  // stage x row (float4)
  const float4* xsrc = reinterpret_cast<const float4*>(x + (size_t)t * H);
  float4* xdst = reinterpret_cast<float4*>(xrow);
  for (int h4 = tid; h4 < H / 4; h4 += 256) xdst[h4] = xsrc[h4];
  __syncthreads();

  const int wave = tid >> 6;
  const int lane = tid & 63;
  const float* Ab = lora_a + ((size_t)(l * E + e)) * R * H;
#pragma unroll
  for (int q = 0; q < 4; ++q) {
    const int r = (wave << 2) | q;
    const float* Ar = Ab + (size_t)r * H;
    float s = 0.f;
    for (int h = lane; h < H; h += 64) s += xrow[h] * Ar[h];
#pragma unroll
    for (int off = 32; off > 0; off >>= 1) s += __shfl_xor(s, off);
    if (lane == 0) a_sh[r] = (r < rank) ? s * sc : 0.f;
  }
  __syncthreads();

  const float* Bb = lora_b + ((size_t)(l * E + e)) * H * R;
  for (int h = tid; h < H; h += 256) {
    const float* Bh = Bb + (size_t)h * R;
    float d = 0.f;
#pragma unroll
    for (int r = 0; r < R; ++r) d += a_sh[r] * Bh[r];
    atomicAdd(out + (size_t)t * H + h, d);
  }
}

extern "C" void kernel_launch(void* const* d_in, const int* in_sizes, int n_in,
                              void* d_out, int out_size, void* d_ws, size_t ws_size,
                              hipStream_t stream) {
  const float* x          = (const float*)d_in[0];
  const int*   topk_ids   = (const int*)d_in[1];
  const float* topk_w     = (const float*)d_in[2];
  const int*   lora_idx   = (const int*)d_in[3];
  const int*   lora_ranks = (const int*)d_in[4];
  const float* scalings   = (const float*)d_in[5];
  const float* w1         = (const float*)d_in[6];
  const float* w2         = (const float*)d_in[7];
  const float* lora_a     = (const float*)d_in[8];
  const float* lora_b     = (const float*)d_in[9];
  float* out = (float*)d_out;

  char* ws = (char*)d_ws;
  int*   eoff   = (int*)(ws);
  int*   pair_t = (int*)(ws + 128);
  int*   pair_e = (int*)(ws + 128 + 4 * P);
  float* pair_w = (float*)(ws + 128 + 8 * P);
  float* act    = (float*)(ws + 32768);

  hipMemsetAsync(d_out, 0, (size_t)T * H * sizeof(float), stream);

  route_kernel<<<1, 256, 0, stream>>>(topk_ids, topk_w, eoff, pair_t, pair_w, pair_e);
  gemm1_silu<<<dim3(P / 64, I / 64, E), 256, 0, stream>>>(x, w1, eoff, pair_t, act);
  gemm2_base<<<dim3(P / 64, H / 64, E), 256, 0, stream>>>(act, w2, eoff, pair_t, pair_w, out);
  lora_kernel<<<P, 256, 0, stream>>>(x, lora_a, lora_b, lora_idx, lora_ranks, scalings,
                                     pair_t, pair_e, out);
}

// Round 2
// 1235.897 us; speedup vs baseline: 2.9734x; 2.9734x over previous
//
#include <hip/hip_runtime.h>
#include <math.h>

constexpr int T = 1024;
constexpr int H = 2048;
constexpr int I = 1024;
constexpr int E = 16;
constexpr int K = 2;
constexpr int L = 4;
constexpr int R = 16;
constexpr int P = T * K;   // 2048 (token,k) pairs

typedef __attribute__((ext_vector_type(8))) short bf16x8;
typedef __attribute__((ext_vector_type(4))) float f32x4;

__device__ inline unsigned short f2bf(float f) {
  unsigned u = __builtin_bit_cast(unsigned, f);
  u = (u + 0x7FFFu + ((u >> 16) & 1u)) >> 16;
  return (unsigned short)u;
}

// load 8 contiguous floats, convert to bf16x8 (RNE)
__device__ inline bf16x8 ldcvt8(const float* __restrict__ p) {
  f32x4 a = *reinterpret_cast<const f32x4*>(p);
  f32x4 b = *reinterpret_cast<const f32x4*>(p + 4);
  bf16x8 v;
  v[0] = (short)f2bf(a[0]); v[1] = (short)f2bf(a[1]);
  v[2] = (short)f2bf(a[2]); v[3] = (short)f2bf(a[3]);
  v[4] = (short)f2bf(b[0]); v[5] = (short)f2bf(b[1]);
  v[6] = (short)f2bf(b[2]); v[7] = (short)f2bf(b[3]);
  return v;
}

// LDS tile: 64 rows x 64 bf16 cols (128B rows), T2 XOR swizzle on byte bit 4-6
__device__ inline void st8(unsigned short* s, int r, int c8, bf16x8 v) {
  int byte = ((r << 6) + c8) * 2;
  byte ^= (r & 7) << 4;
  *reinterpret_cast<bf16x8*>(reinterpret_cast<char*>(s) + byte) = v;
}
__device__ inline bf16x8 ld8(const unsigned short* s, int r, int c8) {
  int byte = ((r << 6) + c8) * 2;
  byte ^= (r & 7) << 4;
  return *reinterpret_cast<const bf16x8*>(reinterpret_cast<const char*>(s) + byte);
}

// ---------------------------------------------------------------------------
// routing: sort (token,k) pairs by expert
// ---------------------------------------------------------------------------
__global__ __launch_bounds__(256) void route_kernel(
    const int* __restrict__ topk_ids, const float* __restrict__ topk_w,
    int* __restrict__ eoff, int* __restrict__ pair_t,
    float* __restrict__ pair_w, int* __restrict__ pair_e) {
  __shared__ int cnt[E];
  __shared__ int off[E + 1];
  __shared__ int cur[E];
  const int tid = threadIdx.x;
  if (tid < E) cnt[tid] = 0;
  __syncthreads();
  for (int p = tid; p < P; p += blockDim.x) atomicAdd(&cnt[topk_ids[p]], 1);
  __syncthreads();
  if (tid == 0) {
    off[0] = 0;
    for (int e = 0; e < E; ++e) off[e + 1] = off[e] + cnt[e];
  }
  __syncthreads();
  if (tid < E) cur[tid] = off[tid];
  if (tid <= E) eoff[tid] = off[tid];
  __syncthreads();
  for (int p = tid; p < P; p += blockDim.x) {
    const int e = topk_ids[p];
    const int pos = atomicAdd(&cur[e], 1);
    pair_t[pos] = p / K;
    pair_w[pos] = topk_w[p];
    pair_e[pos] = e;
  }
}

// ---------------------------------------------------------------------------
// GEMM1 (MFMA bf16): act[p,i] = silu(x·w1_gate) * (x·w1_up), act stored bf16
// tiles 64(pairs) x 64(i) x BK=64 over H
// ---------------------------------------------------------------------------
__global__ __launch_bounds__(256) void gemm1_mfma(
    const float* __restrict__ x, const float* __restrict__ w1,
    const int* __restrict__ eoff, const int* __restrict__ pair_t,
    unsigned short* __restrict__ act) {
  const int e = blockIdx.z;
  const int beg = eoff[e];
  const int cnt = eoff[e + 1] - beg;
  const int m0 = blockIdx.x * 64;
  if (m0 >= cnt) return;
  const int i0 = blockIdx.y * 64;

  __shared__ unsigned short sA[64 * 64];
  __shared__ unsigned short sG[64 * 64];
  __shared__ unsigned short sU[64 * 64];

  const int tid = threadIdx.x;
  const int sr = tid >> 3;          // 0..31 staging row
  const int sc = (tid & 7) << 3;    // col 0..56 (8 elems)

  const int r0 = m0 + sr, r1 = m0 + sr + 32;
  const int tok0 = (r0 < cnt) ? pair_t[beg + r0] : -1;
  const int tok1 = (r1 < cnt) ? pair_t[beg + r1] : -1;
  const float* xr0 = x + (size_t)(tok0 < 0 ? 0 : tok0) * H + sc;
  const float* xr1 = x + (size_t)(tok1 < 0 ? 0 : tok1) * H + sc;
  const float* g0 = w1 + ((size_t)e * (2 * I) + i0 + sr) * H + sc;
  const float* g1 = g0 + (size_t)32 * H;
  const float* u0 = g0 + (size_t)I * H;
  const float* u1 = u0 + (size_t)32 * H;

  const int lane = tid & 63;
  const int wid = tid >> 6;
  const int wm = (wid >> 1) << 5;   // wave m offset (0/32)
  const int wn = (wid & 1) << 5;    // wave n offset (0/32)
  const int fr = lane & 15;
  const int fq = lane >> 4;

  f32x4 ag[2][2], au[2][2];
#pragma unroll
  for (int a = 0; a < 2; ++a)
#pragma unroll
    for (int b = 0; b < 2; ++b) {
      ag[a][b] = {0.f, 0.f, 0.f, 0.f};
      au[a][b] = {0.f, 0.f, 0.f, 0.f};
    }
  bf16x8 zero8 = {0, 0, 0, 0, 0, 0, 0, 0};

  for (int kk = 0; kk < H; kk += 64) {
    bf16x8 va0 = (tok0 >= 0) ? ldcvt8(xr0 + kk) : zero8;
    bf16x8 va1 = (tok1 >= 0) ? ldcvt8(xr1 + kk) : zero8;
    bf16x8 vg0 = ldcvt8(g0 + kk);
    bf16x8 vg1 = ldcvt8(g1 + kk);
    bf16x8 vu0 = ldcvt8(u0 + kk);
    bf16x8 vu1 = ldcvt8(u1 + kk);
    __syncthreads();
    st8(sA, sr, sc, va0); st8(sA, sr + 32, sc, va1);
    st8(sG, sr, sc, vg0); st8(sG, sr + 32, sc, vg1);
    st8(sU, sr, sc, vu0); st8(sU, sr + 32, sc, vu1);
    __syncthreads();
#pragma unroll
    for (int kb = 0; kb < 2; ++kb) {
      const int k8 = (kb << 5) + (fq << 3);
      bf16x8 af[2], gf[2], uf[2];
#pragma unroll
      for (int mi = 0; mi < 2; ++mi) af[mi] = ld8(sA, wm + (mi << 4) + fr, k8);
#pragma unroll
      for (int nj = 0; nj < 2; ++nj) {
        gf[nj] = ld8(sG, wn + (nj << 4) + fr, k8);
        uf[nj] = ld8(sU, wn + (nj << 4) + fr, k8);
      }
#pragma unroll
      for (int mi = 0; mi < 2; ++mi)
#pragma unroll
        for (int nj = 0; nj < 2; ++nj) {
          ag[mi][nj] = __builtin_amdgcn_mfma_f32_16x16x32_bf16(af[mi], gf[nj], ag[mi][nj], 0, 0, 0);
          au[mi][nj] = __builtin_amdgcn_mfma_f32_16x16x32_bf16(af[mi], uf[nj], au[mi][nj], 0, 0, 0);
        }
    }
  }

  // epilogue: silu(gate)*up -> bf16 act  (C/D: col=lane&15, row=(lane>>4)*4+q)
#pragma unroll
  for (int mi = 0; mi < 2; ++mi)
#pragma unroll
    for (int q = 0; q < 4; ++q) {
      const int m = m0 + wm + (mi << 4) + (fq << 2) + q;
      if (m >= cnt) continue;
#pragma unroll
      for (int nj = 0; nj < 2; ++nj) {
        const float g = ag[mi][nj][q];
        const float u = au[mi][nj][q];
        const float s = g / (1.f + __expf(-g));
        act[(size_t)(beg + m) * I + i0 + wn + (nj << 4) + fr] = f2bf(s * u);
      }
    }
}

// ---------------------------------------------------------------------------
// GEMM2 (MFMA bf16): out[t,h] += pw * (act[p,:]·w2[e,h,:])
// tiles 64(pairs) x 64(h) x BK=64 over I
// ---------------------------------------------------------------------------
__global__ __launch_bounds__(256) void gemm2_mfma(
    const unsigned short* __restrict__ act, const float* __restrict__ w2,
    const int* __restrict__ eoff, const int* __restrict__ pair_t,
    const float* __restrict__ pair_w, float* __restrict__ out) {
  const int e = blockIdx.z;
  const int beg = eoff[e];
  const int cnt = eoff[e + 1] - beg;
  const int m0 = blockIdx.x * 64;
  if (m0 >= cnt) return;
  const int h0 = blockIdx.y * 64;

  __shared__ unsigned short sA[64 * 64];
  __shared__ unsigned short sB[64 * 64];

  const int tid = threadIdx.x;
  const int sr = tid >> 3;
  const int sc = (tid & 7) << 3;

  const int r0 = m0 + sr, r1 = m0 + sr + 32;
  const bool v0 = r0 < cnt, v1 = r1 < cnt;
  const unsigned short* a0 = act + (size_t)(beg + (v0 ? r0 : 0)) * I + sc;
  const unsigned short* a1 = act + (size_t)(beg + (v1 ? r1 : 0)) * I + sc;
  const float* b0 = w2 + ((size_t)e * H + h0 + sr) * I + sc;
  const float* b1 = b0 + (size_t)32 * I;

  const int lane = tid & 63;
  const int wid = tid >> 6;
  const int wm = (wid >> 1) << 5;
  const int wn = (wid & 1) << 5;
  const int fr = lane & 15;
  const int fq = lane >> 4;

  f32x4 acc[2][2];
#pragma unroll
  for (int a = 0; a < 2; ++a)
#pragma unroll
    for (int b = 0; b < 2; ++b) acc[a][b] = {0.f, 0.f, 0.f, 0.f};
  bf16x8 zero8 = {0, 0, 0, 0, 0, 0, 0, 0};

  for (int kk = 0; kk < I; kk += 64) {
    bf16x8 va0 = v0 ? *reinterpret_cast<const bf16x8*>(a0 + kk) : zero8;
    bf16x8 va1 = v1 ? *reinterpret_cast<const bf16x8*>(a1 + kk) : zero8;
    bf16x8 vb0 = ldcvt8(b0 + kk);
    bf16x8 vb1 = ldcvt8(b1 + kk);
    __syncthreads();
    st8(sA, sr, sc, va0); st8(sA, sr + 32, sc, va1);
    st8(sB, sr, sc, vb0); st8(sB, sr + 32, sc, vb1);
    __syncthreads();
#pragma unroll
    for (int kb = 0; kb < 2; ++kb) {
      const int k8 = (kb << 5) + (fq << 3);
      bf16x8 af[2], bf[2];
#pragma unroll
      for (int mi = 0; mi < 2; ++mi) af[mi] = ld8(sA, wm + (mi << 4) + fr, k8);
#pragma unroll
      for (int nj = 0; nj < 2; ++nj) bf[nj] = ld8(sB, wn + (nj << 4) + fr, k8);
#pragma unroll
      for (int mi = 0; mi < 2; ++mi)
#pragma unroll
        for (int nj = 0; nj < 2; ++nj)
          acc[mi][nj] = __builtin_amdgcn_mfma_f32_16x16x32_bf16(af[mi], bf[nj], acc[mi][nj], 0, 0, 0);
    }
  }

#pragma unroll
  for (int mi = 0; mi < 2; ++mi)
#pragma unroll
    for (int q = 0; q < 4; ++q) {
      const int m = m0 + wm + (mi << 4) + (fq << 2) + q;
      if (m >= cnt) continue;
      const int t = pair_t[beg + m];
      const float w = pair_w[beg + m];
#pragma unroll
      for (int nj = 0; nj < 2; ++nj)
        atomicAdd(out + (size_t)t * H + h0 + wn + (nj << 4) + fr, w * acc[mi][nj][q]);
    }
}

// ---------------------------------------------------------------------------
// LoRA delta (fp32, vectorized): out[t] += sc * (x[t]·A^T masked) · B^T
// ---------------------------------------------------------------------------
__global__ __launch_bounds__(256) void lora_kernel(
    const float* __restrict__ x, const float* __restrict__ lora_a,
    const float* __restrict__ lora_b, const int* __restrict__ lora_idx,
    const int* __restrict__ lora_ranks, const float* __restrict__ scalings,
    const int* __restrict__ pair_t, const int* __restrict__ pair_e,
    float* __restrict__ out) {
  const int p = blockIdx.x;
  const int t = pair_t[p];
  const int e = pair_e[p];
  const int l = lora_idx[t];
  if (l < 0) return;
  int rank = lora_ranks[l];
  if (rank < 1) rank = 1;
  const float sc = scalings[l];

  __shared__ float a_sh[R];
  const int tid = threadIdx.x;
  const int wave = tid >> 6, lane = tid & 63;
  const float4* xv = reinterpret_cast<const float4*>(x + (size_t)t * H);
  const float* Ab = lora_a + (size_t)(l * E + e) * R * H;
#pragma unroll
  for (int q = 0; q < 4; ++q) {
    const int r = (wave << 2) | q;
    const float4* Av = reinterpret_cast<const float4*>(Ab + (size_t)r * H);
    float s = 0.f;
#pragma unroll
    for (int it = 0; it < H / 256; ++it) {
      const int h4 = it * 64 + lane;
      const float4 xx = xv[h4];
      const float4 aa = Av[h4];
      s += xx.x * aa.x + xx.y * aa.y + xx.z * aa.z + xx.w * aa.w;
    }
#pragma unroll
    for (int off = 32; off; off >>= 1) s += __shfl_xor(s, off);
    if (lane == 0) a_sh[r] = (r < rank) ? s * sc : 0.f;
  }
  __syncthreads();
  const float* Bb = lora_b + (size_t)(l * E + e) * H * R;
  for (int h = tid; h < H; h += 256) {
    const float4* Bv = reinterpret_cast<const float4*>(Bb + (size_t)h * R);
    float d = 0.f;
#pragma unroll
    for (int r4 = 0; r4 < 4; ++r4) {
      const float4 bb = Bv[r4];
      d += a_sh[r4 * 4 + 0] * bb.x + a_sh[r4 * 4 + 1] * bb.y +
           a_sh[r4 * 4 + 2] * bb.z + a_sh[r4 * 4 + 3] * bb.w;
    }
    atomicAdd(out + (size_t)t * H + h, d);
  }
}

extern "C" void kernel_launch(void* const* d_in, const int* in_sizes, int n_in,
                              void* d_out, int out_size, void* d_ws, size_t ws_size,
                              hipStream_t stream) {
  const float* x          = (const float*)d_in[0];
  const int*   topk_ids   = (const int*)d_in[1];
  const float* topk_w     = (const float*)d_in[2];
  const int*   lora_idx   = (const int*)d_in[3];
  const int*   lora_ranks = (const int*)d_in[4];
  const float* scalings   = (const float*)d_in[5];
  const float* w1         = (const float*)d_in[6];
  const float* w2         = (const float*)d_in[7];
  const float* lora_a     = (const float*)d_in[8];
  const float* lora_b     = (const float*)d_in[9];
  float* out = (float*)d_out;

  char* ws = (char*)d_ws;
  int*   eoff   = (int*)(ws);
  int*   pair_t = (int*)(ws + 128);
  int*   pair_e = (int*)(ws + 128 + 4 * P);
  float* pair_w = (float*)(ws + 128 + 8 * P);
  unsigned short* act = (unsigned short*)(ws + 32768);   // P*I bf16 = 4MB

  hipMemsetAsync(d_out, 0, (size_t)T * H * sizeof(float), stream);

  route_kernel<<<1, 256, 0, stream>>>(topk_ids, topk_w, eoff, pair_t, pair_w, pair_e);
  gemm1_mfma<<<dim3(P / 64, I / 64, E), 256, 0, stream>>>(x, w1, eoff, pair_t, act);
  gemm2_mfma<<<dim3(P / 64, H / 64, E), 256, 0, stream>>>(act, w2, eoff, pair_t, pair_w, out);
  lora_kernel<<<P, 256, 0, stream>>>(x, lora_a, lora_b, lora_idx, lora_ranks, scalings,
                                     pair_t, pair_e, out);
}

// Round 3
// 917.353 us; speedup vs baseline: 4.0060x; 1.3472x over previous
//
#include <hip/hip_runtime.h>
#include <math.h>

constexpr int T = 1024;
constexpr int H = 2048;
constexpr int I = 1024;
constexpr int E = 16;
constexpr int K = 2;
constexpr int L = 4;
constexpr int R = 16;
constexpr int P = T * K;   // 2048 (token,k) pairs

typedef __attribute__((ext_vector_type(8))) short bf16x8;
typedef __attribute__((ext_vector_type(4))) float f32x4;

__device__ inline unsigned short f2bf(float f) {
  unsigned u = __builtin_bit_cast(unsigned, f);
  u = (u + 0x7FFFu + ((u >> 16) & 1u)) >> 16;
  return (unsigned short)u;
}

__device__ inline bf16x8 pack8(f32x4 a, f32x4 b) {
  bf16x8 v;
  v[0] = (short)f2bf(a[0]); v[1] = (short)f2bf(a[1]);
  v[2] = (short)f2bf(a[2]); v[3] = (short)f2bf(a[3]);
  v[4] = (short)f2bf(b[0]); v[5] = (short)f2bf(b[1]);
  v[6] = (short)f2bf(b[2]); v[7] = (short)f2bf(b[3]);
  return v;
}

// LDS tile with 64 bf16 cols per row (128B rows); T2 XOR swizzle (verified 0 conflicts)
__device__ inline void st8(unsigned short* s, int r, int c, bf16x8 v) {
  int byte = ((r << 6) + c) * 2;
  byte ^= (r & 7) << 4;
  *reinterpret_cast<bf16x8*>(reinterpret_cast<char*>(s) + byte) = v;
}
__device__ inline bf16x8 ld8(const unsigned short* s, int r, int c) {
  int byte = ((r << 6) + c) * 2;
  byte ^= (r & 7) << 4;
  return *reinterpret_cast<const bf16x8*>(reinterpret_cast<const char*>(s) + byte);
}

// ---------------------------------------------------------------------------
__global__ __launch_bounds__(256) void route_kernel(
    const int* __restrict__ topk_ids, const float* __restrict__ topk_w,
    int* __restrict__ eoff, int* __restrict__ pair_t,
    float* __restrict__ pair_w, int* __restrict__ pair_e) {
  __shared__ int cnt[E];
  __shared__ int off[E + 1];
  __shared__ int cur[E];
  const int tid = threadIdx.x;
  if (tid < E) cnt[tid] = 0;
  __syncthreads();
  for (int p = tid; p < P; p += blockDim.x) atomicAdd(&cnt[topk_ids[p]], 1);
  __syncthreads();
  if (tid == 0) {
    off[0] = 0;
    for (int e = 0; e < E; ++e) off[e + 1] = off[e] + cnt[e];
  }
  __syncthreads();
  if (tid < E) cur[tid] = off[tid];
  if (tid <= E) eoff[tid] = off[tid];
  __syncthreads();
  for (int p = tid; p < P; p += blockDim.x) {
    const int e = topk_ids[p];
    const int pos = atomicAdd(&cur[e], 1);
    pair_t[pos] = p / K;
    pair_w[pos] = topk_w[p];
    pair_e[pos] = e;
  }
}

// x (fp32) -> xb (bf16), whole tensor
__global__ __launch_bounds__(256) void xcvt(const float* __restrict__ x,
                                            unsigned short* __restrict__ xb) {
  const int i = (blockIdx.x * 256 + threadIdx.x) * 8;
  f32x4 a = *reinterpret_cast<const f32x4*>(x + i);
  f32x4 b = *reinterpret_cast<const f32x4*>(x + i + 4);
  *reinterpret_cast<bf16x8*>(xb + i) = pack8(a, b);
}

// ---------------------------------------------------------------------------
// GEMM1: act[p,i] = silu(x·w1_gate)*(x·w1_up).  BM=128 x BN=64 x BK=64.
// 2-phase pipeline: next tile's global loads issued into regs before the
// compute barrier (register loads fly across barriers).
// ---------------------------------------------------------------------------
__global__ __launch_bounds__(256) void gemm1_mfma(
    const unsigned short* __restrict__ xb, const float* __restrict__ w1,
    const int* __restrict__ eoff, const int* __restrict__ pair_t,
    unsigned short* __restrict__ act) {
  const int e = blockIdx.z;
  const int beg = eoff[e];
  const int cnt = eoff[e + 1] - beg;
  const int m0 = blockIdx.x * 128;
  if (m0 >= cnt) return;
  const int i0 = blockIdx.y * 64;

  __shared__ unsigned short sX[128 * 64];
  __shared__ unsigned short sG[64 * 64];
  __shared__ unsigned short sU[64 * 64];

  const int tid = threadIdx.x;
  const int xr = tid >> 1, xc = (tid & 1) * 32;   // x stage: 2 thr/row, 32 cols each
  const int gr = tid >> 2, gc = (tid & 3) * 16;   // g/u stage: 4 thr/row, 16 cols each

  const int rm = m0 + xr;
  const int tok = (rm < cnt) ? pair_t[beg + rm] : -1;
  const unsigned short* xrow = xb + (size_t)(tok < 0 ? 0 : tok) * H + xc;
  const float* grow = w1 + ((size_t)e * (2 * I) + i0 + gr) * H + gc;
  const float* urow = grow + (size_t)I * H;

  const int lane = tid & 63, wid = tid >> 6;
  const int wm = wid << 5;            // wave owns rows [wm, wm+32)
  const int fr = lane & 15, fq = lane >> 4;

  f32x4 ag[2][4], au[2][4];
#pragma unroll
  for (int a = 0; a < 2; ++a)
#pragma unroll
    for (int b = 0; b < 4; ++b) {
      ag[a][b] = {0.f, 0.f, 0.f, 0.f};
      au[a][b] = {0.f, 0.f, 0.f, 0.f};
    }

  bf16x8 rx[4];
  f32x4 rg[4], ru[4];
  const bf16x8 zero8 = {0, 0, 0, 0, 0, 0, 0, 0};

  auto LOAD = [&](int kk) {
    if (tok >= 0) {
#pragma unroll
      for (int s = 0; s < 4; ++s)
        rx[s] = *reinterpret_cast<const bf16x8*>(xrow + kk + s * 8);
    } else {
#pragma unroll
      for (int s = 0; s < 4; ++s) rx[s] = zero8;
    }
#pragma unroll
    for (int s = 0; s < 4; ++s) {
      rg[s] = *reinterpret_cast<const f32x4*>(grow + kk + s * 4);
      ru[s] = *reinterpret_cast<const f32x4*>(urow + kk + s * 4);
    }
  };

  constexpr int NT = H / 64;
  LOAD(0);
  for (int t = 0; t < NT; ++t) {
    const bf16x8 wg0 = pack8(rg[0], rg[1]), wg1 = pack8(rg[2], rg[3]);
    const bf16x8 wu0 = pack8(ru[0], ru[1]), wu1 = pack8(ru[2], ru[3]);
    __syncthreads();   // previous step's readers done
    st8(sX, xr, xc + 0, rx[0]); st8(sX, xr, xc + 8, rx[1]);
    st8(sX, xr, xc + 16, rx[2]); st8(sX, xr, xc + 24, rx[3]);
    st8(sG, gr, gc, wg0); st8(sG, gr, gc + 8, wg1);
    st8(sU, gr, gc, wu0); st8(sU, gr, gc + 8, wu1);
    if (t + 1 < NT) LOAD((t + 1) * 64);   // fly across barrier + compute
    __syncthreads();
#pragma unroll
    for (int kb = 0; kb < 2; ++kb) {
      const int k8 = (kb << 5) + (fq << 3);
      bf16x8 af[2], gf[4], uf[4];
#pragma unroll
      for (int mi = 0; mi < 2; ++mi) af[mi] = ld8(sX, wm + (mi << 4) + fr, k8);
#pragma unroll
      for (int nj = 0; nj < 4; ++nj) {
        gf[nj] = ld8(sG, (nj << 4) + fr, k8);
        uf[nj] = ld8(sU, (nj << 4) + fr, k8);
      }
#pragma unroll
      for (int mi = 0; mi < 2; ++mi)
#pragma unroll
        for (int nj = 0; nj < 4; ++nj) {
          ag[mi][nj] = __builtin_amdgcn_mfma_f32_16x16x32_bf16(af[mi], gf[nj], ag[mi][nj], 0, 0, 0);
          au[mi][nj] = __builtin_amdgcn_mfma_f32_16x16x32_bf16(af[mi], uf[nj], au[mi][nj], 0, 0, 0);
        }
    }
  }

  // epilogue: C/D layout col=lane&15, row=(lane>>4)*4+q
#pragma unroll
  for (int mi = 0; mi < 2; ++mi)
#pragma unroll
    for (int q = 0; q < 4; ++q) {
      const int m = m0 + wm + (mi << 4) + (fq << 2) + q;
      if (m >= cnt) continue;
#pragma unroll
      for (int nj = 0; nj < 4; ++nj) {
        const float g = ag[mi][nj][q];
        const float u = au[mi][nj][q];
        const float s = g / (1.f + __expf(-g));
        act[(size_t)(beg + m) * I + i0 + (nj << 4) + fr] = f2bf(s * u);
      }
    }
}

// ---------------------------------------------------------------------------
// GEMM2: out[t,h] += pw * (act[p,:]·w2[e,h,:]).  BM=128 x BN=64 x BK=64.
// ---------------------------------------------------------------------------
__global__ __launch_bounds__(256) void gemm2_mfma(
    const unsigned short* __restrict__ act, const float* __restrict__ w2,
    const int* __restrict__ eoff, const int* __restrict__ pair_t,
    const float* __restrict__ pair_w, float* __restrict__ out) {
  const int e = blockIdx.z;
  const int beg = eoff[e];
  const int cnt = eoff[e + 1] - beg;
  const int m0 = blockIdx.x * 128;
  if (m0 >= cnt) return;
  const int h0 = blockIdx.y * 64;

  __shared__ unsigned short sA[128 * 64];
  __shared__ unsigned short sB[64 * 64];

  const int tid = threadIdx.x;
  const int ar = tid >> 1, ac = (tid & 1) * 32;
  const int br = tid >> 2, bc = (tid & 3) * 16;

  const bool av = (m0 + ar) < cnt;
  const unsigned short* arow = act + (size_t)(beg + (av ? m0 + ar : 0)) * I + ac;
  const float* brow = w2 + ((size_t)e * H + h0 + br) * I + bc;

  const int lane = tid & 63, wid = tid >> 6;
  const int wm = wid << 5;
  const int fr = lane & 15, fq = lane >> 4;

  f32x4 acc[2][4];
#pragma unroll
  for (int a = 0; a < 2; ++a)
#pragma unroll
    for (int b = 0; b < 4; ++b) acc[a][b] = {0.f, 0.f, 0.f, 0.f};

  bf16x8 ra[4];
  f32x4 rb[4];

  auto LOAD = [&](int kk) {
#pragma unroll
    for (int s = 0; s < 4; ++s) {
      ra[s] = *reinterpret_cast<const bf16x8*>(arow + kk + s * 8);
      rb[s] = *reinterpret_cast<const f32x4*>(brow + kk + s * 4);
    }
  };

  constexpr int NT = I / 64;
  LOAD(0);
  for (int t = 0; t < NT; ++t) {
    const bf16x8 wb0 = pack8(rb[0], rb[1]), wb1 = pack8(rb[2], rb[3]);
    __syncthreads();
    st8(sA, ar, ac + 0, ra[0]); st8(sA, ar, ac + 8, ra[1]);
    st8(sA, ar, ac + 16, ra[2]); st8(sA, ar, ac + 24, ra[3]);
    st8(sB, br, bc, wb0); st8(sB, br, bc + 8, wb1);
    if (t + 1 < NT) LOAD((t + 1) * 64);
    __syncthreads();
#pragma unroll
    for (int kb = 0; kb < 2; ++kb) {
      const int k8 = (kb << 5) + (fq << 3);
      bf16x8 af[2], bf[4];
#pragma unroll
      for (int mi = 0; mi < 2; ++mi) af[mi] = ld8(sA, wm + (mi << 4) + fr, k8);
#pragma unroll
      for (int nj = 0; nj < 4; ++nj) bf[nj] = ld8(sB, (nj << 4) + fr, k8);
#pragma unroll
      for (int mi = 0; mi < 2; ++mi)
#pragma unroll
        for (int nj = 0; nj < 4; ++nj)
          acc[mi][nj] = __builtin_amdgcn_mfma_f32_16x16x32_bf16(af[mi], bf[nj], acc[mi][nj], 0, 0, 0);
    }
  }

#pragma unroll
  for (int mi = 0; mi < 2; ++mi)
#pragma unroll
    for (int q = 0; q < 4; ++q) {
      const int m = m0 + wm + (mi << 4) + (fq << 2) + q;
      if (m >= cnt) continue;
      const int tt = pair_t[beg + m];
      const float w = pair_w[beg + m];
#pragma unroll
      for (int nj = 0; nj < 4; ++nj)
        atomicAdd(out + (size_t)tt * H + h0 + (nj << 4) + fr, w * acc[mi][nj][q]);
    }
}

// ---------------------------------------------------------------------------
// LoRA delta (fp32): out[t] += sc * (x[t]·A^T masked) · B^T
// ---------------------------------------------------------------------------
__global__ __launch_bounds__(256) void lora_kernel(
    const float* __restrict__ x, const float* __restrict__ lora_a,
    const float* __restrict__ lora_b, const int* __restrict__ lora_idx,
    const int* __restrict__ lora_ranks, const float* __restrict__ scalings,
    const int* __restrict__ pair_t, const int* __restrict__ pair_e,
    float* __restrict__ out) {
  const int p = blockIdx.x;
  const int t = pair_t[p];
  const int e = pair_e[p];
  const int l = lora_idx[t];
  if (l < 0) return;
  int rank = lora_ranks[l];
  if (rank < 1) rank = 1;
  const float sc = scalings[l];

  __shared__ float a_sh[R];
  const int tid = threadIdx.x;
  const int wave = tid >> 6, lane = tid & 63;
  const float4* xv = reinterpret_cast<const float4*>(x + (size_t)t * H);
  const float* Ab = lora_a + (size_t)(l * E + e) * R * H;
#pragma unroll
  for (int q = 0; q < 4; ++q) {
    const int r = (wave << 2) | q;
    const float4* Av = reinterpret_cast<const float4*>(Ab + (size_t)r * H);
    float s = 0.f;
#pragma unroll
    for (int it = 0; it < H / 256; ++it) {
      const int h4 = it * 64 + lane;
      const float4 xx = xv[h4];
      const float4 aa = Av[h4];
      s += xx.x * aa.x + xx.y * aa.y + xx.z * aa.z + xx.w * aa.w;
    }
#pragma unroll
    for (int off = 32; off; off >>= 1) s += __shfl_xor(s, off);
    if (lane == 0) a_sh[r] = (r < rank) ? s * sc : 0.f;
  }
  __syncthreads();
  const float* Bb = lora_b + (size_t)(l * E + e) * H * R;
  for (int h = tid; h < H; h += 256) {
    const float4* Bv = reinterpret_cast<const float4*>(Bb + (size_t)h * R);
    float d = 0.f;
#pragma unroll
    for (int r4 = 0; r4 < 4; ++r4) {
      const float4 bb = Bv[r4];
      d += a_sh[r4 * 4 + 0] * bb.x + a_sh[r4 * 4 + 1] * bb.y +
           a_sh[r4 * 4 + 2] * bb.z + a_sh[r4 * 4 + 3] * bb.w;
    }
    atomicAdd(out + (size_t)t * H + h, d);
  }
}

extern "C" void kernel_launch(void* const* d_in, const int* in_sizes, int n_in,
                              void* d_out, int out_size, void* d_ws, size_t ws_size,
                              hipStream_t stream) {
  const float* x          = (const float*)d_in[0];
  const int*   topk_ids   = (const int*)d_in[1];
  const float* topk_w     = (const float*)d_in[2];
  const int*   lora_idx   = (const int*)d_in[3];
  const int*   lora_ranks = (const int*)d_in[4];
  const float* scalings   = (const float*)d_in[5];
  const float* w1         = (const float*)d_in[6];
  const float* w2         = (const float*)d_in[7];
  const float* lora_a     = (const float*)d_in[8];
  const float* lora_b     = (const float*)d_in[9];
  float* out = (float*)d_out;

  char* ws = (char*)d_ws;
  int*   eoff   = (int*)(ws);
  int*   pair_t = (int*)(ws + 128);
  int*   pair_e = (int*)(ws + 128 + 4 * P);
  float* pair_w = (float*)(ws + 128 + 8 * P);
  unsigned short* xb  = (unsigned short*)(ws + 32768);                        // T*H bf16 = 4MB
  unsigned short* act = (unsigned short*)(ws + 32768 + (size_t)T * H * 2);    // P*I bf16 = 4MB

  hipMemsetAsync(d_out, 0, (size_t)T * H * sizeof(float), stream);

  xcvt<<<T * H / (256 * 8), 256, 0, stream>>>(x, xb);
  route_kernel<<<1, 256, 0, stream>>>(topk_ids, topk_w, eoff, pair_t, pair_w, pair_e);
  gemm1_mfma<<<dim3(P / 128, I / 64, E), 256, 0, stream>>>(xb, w1, eoff, pair_t, act);
  gemm2_mfma<<<dim3(P / 128, H / 64, E), 256, 0, stream>>>(act, w2, eoff, pair_t, pair_w, out);
  lora_kernel<<<P, 256, 0, stream>>>(x, lora_a, lora_b, lora_idx, lora_ranks, scalings,
                                     pair_t, pair_e, out);
}

// Round 4
// 210.018 us; speedup vs baseline: 17.4979x; 4.3680x over previous
//
#include <hip/hip_runtime.h>
#include <math.h>

constexpr int T = 1024;
constexpr int H = 2048;
constexpr int I = 1024;
constexpr int E = 16;
constexpr int K = 2;
constexpr int L = 4;
constexpr int R = 16;
constexpr int P = T * K;        // 2048 (token,k) pairs
constexpr int MT_MAX = 32;      // max m-tiles (BM=128): worst case 16 + 15

typedef __attribute__((ext_vector_type(8))) short bf16x8;
typedef __attribute__((ext_vector_type(4))) float f32x4;

__device__ inline unsigned short f2bf(float f) {
  unsigned u = __builtin_bit_cast(unsigned, f);
  u = (u + 0x7FFFu + ((u >> 16) & 1u)) >> 16;
  return (unsigned short)u;
}

__device__ inline bf16x8 pack8(f32x4 a, f32x4 b) {
  bf16x8 v;
  v[0] = (short)f2bf(a[0]); v[1] = (short)f2bf(a[1]);
  v[2] = (short)f2bf(a[2]); v[3] = (short)f2bf(a[3]);
  v[4] = (short)f2bf(b[0]); v[5] = (short)f2bf(b[1]);
  v[6] = (short)f2bf(b[2]); v[7] = (short)f2bf(b[3]);
  return v;
}

// LDS tile, 64 bf16 cols per row (128B rows); XOR swizzle (0 conflicts, verified)
__device__ inline void st8(unsigned short* s, int r, int c, bf16x8 v) {
  int byte = ((r << 6) + c) * 2;
  byte ^= (r & 7) << 4;
  *reinterpret_cast<bf16x8*>(reinterpret_cast<char*>(s) + byte) = v;
}
__device__ inline bf16x8 ld8(const unsigned short* s, int r, int c) {
  int byte = ((r << 6) + c) * 2;
  byte ^= (r & 7) << 4;
  return *reinterpret_cast<const bf16x8*>(reinterpret_cast<const char*>(s) + byte);
}

// ---------------------------------------------------------------------------
// routing: sort (token,k) pairs by expert + emit compact m-tile table
// ---------------------------------------------------------------------------
__global__ __launch_bounds__(256) void route_kernel(
    const int* __restrict__ topk_ids, const float* __restrict__ topk_w,
    int* __restrict__ eoff, int* __restrict__ pair_t,
    float* __restrict__ pair_w, int* __restrict__ pair_e,
    int* __restrict__ tile_e, int* __restrict__ tile_m0, int* __restrict__ ntiles) {
  __shared__ int cnt[E];
  __shared__ int off[E + 1];
  __shared__ int cur[E];
  const int tid = threadIdx.x;
  if (tid < E) cnt[tid] = 0;
  __syncthreads();
  for (int p = tid; p < P; p += blockDim.x) atomicAdd(&cnt[topk_ids[p]], 1);
  __syncthreads();
  if (tid == 0) {
    off[0] = 0;
    for (int e = 0; e < E; ++e) off[e + 1] = off[e] + cnt[e];
    int nt = 0;
    for (int e = 0; e < E; ++e)
      for (int m0 = 0; m0 < cnt[e]; m0 += 128) {
        tile_e[nt] = e;
        tile_m0[nt] = m0;
        ++nt;
      }
    *ntiles = nt;
  }
  __syncthreads();
  if (tid < E) cur[tid] = off[tid];
  if (tid <= E) eoff[tid] = off[tid];
  __syncthreads();
  for (int p = tid; p < P; p += blockDim.x) {
    const int e = topk_ids[p];
    const int pos = atomicAdd(&cur[e], 1);
    pair_t[pos] = p / K;
    pair_w[pos] = topk_w[p];
    pair_e[pos] = e;
  }
}

// x (fp32) -> xb (bf16)
__global__ __launch_bounds__(256) void xcvt(const float* __restrict__ x,
                                            unsigned short* __restrict__ xb) {
  const int i = (blockIdx.x * 256 + threadIdx.x) * 8;
  f32x4 a = *reinterpret_cast<const f32x4*>(x + i);
  f32x4 b = *reinterpret_cast<const f32x4*>(x + i + 4);
  *reinterpret_cast<bf16x8*>(xb + i) = pack8(a, b);
}

// ---------------------------------------------------------------------------
// GEMM1: act[p,i] = silu(x·w1_gate)*(x·w1_up).  BM=128 x BN=64 x BK=64.
// 1-D compact grid: bid = mt*16 + it  (all blocks are real work)
// ---------------------------------------------------------------------------
__global__ __launch_bounds__(256) void gemm1_mfma(
    const unsigned short* __restrict__ xb, const float* __restrict__ w1,
    const int* __restrict__ eoff, const int* __restrict__ pair_t,
    const int* __restrict__ tile_e, const int* __restrict__ tile_m0,
    const int* __restrict__ ntiles, unsigned short* __restrict__ act) {
  const int bid = blockIdx.x;
  const int mt = bid >> 4;
  if (mt >= *ntiles) return;
  const int it = bid & 15;
  const int e = tile_e[mt];
  const int m0 = tile_m0[mt];
  const int beg = eoff[e];
  const int cnt = eoff[e + 1] - beg;
  const int i0 = it * 64;

  __shared__ unsigned short sX[128 * 64];
  __shared__ unsigned short sG[64 * 64];
  __shared__ unsigned short sU[64 * 64];

  const int tid = threadIdx.x;
  const int xr = tid >> 1, xc = (tid & 1) * 32;
  const int gr = tid >> 2, gc = (tid & 3) * 16;

  const int rm = m0 + xr;
  const int tok = (rm < cnt) ? pair_t[beg + rm] : -1;
  const unsigned short* xrow = xb + (size_t)(tok < 0 ? 0 : tok) * H + xc;
  const float* grow = w1 + ((size_t)e * (2 * I) + i0 + gr) * H + gc;
  const float* urow = grow + (size_t)I * H;

  const int lane = tid & 63, wid = tid >> 6;
  const int wm = wid << 5;
  const int fr = lane & 15, fq = lane >> 4;

  f32x4 ag[2][4], au[2][4];
#pragma unroll
  for (int a = 0; a < 2; ++a)
#pragma unroll
    for (int b = 0; b < 4; ++b) {
      ag[a][b] = {0.f, 0.f, 0.f, 0.f};
      au[a][b] = {0.f, 0.f, 0.f, 0.f};
    }

  bf16x8 rx[4];
  f32x4 rg[4], ru[4];
  const bf16x8 zero8 = {0, 0, 0, 0, 0, 0, 0, 0};

  auto LOAD = [&](int kk) {
    if (tok >= 0) {
#pragma unroll
      for (int s = 0; s < 4; ++s)
        rx[s] = *reinterpret_cast<const bf16x8*>(xrow + kk + s * 8);
    } else {
#pragma unroll
      for (int s = 0; s < 4; ++s) rx[s] = zero8;
    }
#pragma unroll
    for (int s = 0; s < 4; ++s) {
      rg[s] = *reinterpret_cast<const f32x4*>(grow + kk + s * 4);
      ru[s] = *reinterpret_cast<const f32x4*>(urow + kk + s * 4);
    }
  };

  constexpr int NT = H / 64;
  LOAD(0);
  for (int t = 0; t < NT; ++t) {
    const bf16x8 wg0 = pack8(rg[0], rg[1]), wg1 = pack8(rg[2], rg[3]);
    const bf16x8 wu0 = pack8(ru[0], ru[1]), wu1 = pack8(ru[2], ru[3]);
    __syncthreads();
    st8(sX, xr, xc + 0, rx[0]); st8(sX, xr, xc + 8, rx[1]);
    st8(sX, xr, xc + 16, rx[2]); st8(sX, xr, xc + 24, rx[3]);
    st8(sG, gr, gc, wg0); st8(sG, gr, gc + 8, wg1);
    st8(sU, gr, gc, wu0); st8(sU, gr, gc + 8, wu1);
    if (t + 1 < NT) LOAD((t + 1) * 64);
    __syncthreads();
#pragma unroll
    for (int kb = 0; kb < 2; ++kb) {
      const int k8 = (kb << 5) + (fq << 3);
      bf16x8 af[2], gf[4], uf[4];
#pragma unroll
      for (int mi = 0; mi < 2; ++mi) af[mi] = ld8(sX, wm + (mi << 4) + fr, k8);
#pragma unroll
      for (int nj = 0; nj < 4; ++nj) {
        gf[nj] = ld8(sG, (nj << 4) + fr, k8);
        uf[nj] = ld8(sU, (nj << 4) + fr, k8);
      }
#pragma unroll
      for (int mi = 0; mi < 2; ++mi)
#pragma unroll
        for (int nj = 0; nj < 4; ++nj) {
          ag[mi][nj] = __builtin_amdgcn_mfma_f32_16x16x32_bf16(af[mi], gf[nj], ag[mi][nj], 0, 0, 0);
          au[mi][nj] = __builtin_amdgcn_mfma_f32_16x16x32_bf16(af[mi], uf[nj], au[mi][nj], 0, 0, 0);
        }
    }
  }

#pragma unroll
  for (int mi = 0; mi < 2; ++mi)
#pragma unroll
    for (int q = 0; q < 4; ++q) {
      const int m = m0 + wm + (mi << 4) + (fq << 2) + q;
      if (m >= cnt) continue;
#pragma unroll
      for (int nj = 0; nj < 4; ++nj) {
        const float g = ag[mi][nj][q];
        const float u = au[mi][nj][q];
        const float s = g / (1.f + __expf(-g));
        act[(size_t)(beg + m) * I + i0 + (nj << 4) + fr] = f2bf(s * u);
      }
    }
}

// ---------------------------------------------------------------------------
// GEMM2: out[t,h] += pw * (act[p,:]·w2[e,h,:]).  BM=128 x BN=64 x BK=64.
// 1-D compact grid: bid = mt*32 + ht
// ---------------------------------------------------------------------------
__global__ __launch_bounds__(256) void gemm2_mfma(
    const unsigned short* __restrict__ act, const float* __restrict__ w2,
    const int* __restrict__ eoff, const int* __restrict__ pair_t,
    const float* __restrict__ pair_w, const int* __restrict__ tile_e,
    const int* __restrict__ tile_m0, const int* __restrict__ ntiles,
    float* __restrict__ out) {
  const int bid = blockIdx.x;
  const int mt = bid >> 5;
  if (mt >= *ntiles) return;
  const int ht = bid & 31;
  const int e = tile_e[mt];
  const int m0 = tile_m0[mt];
  const int beg = eoff[e];
  const int cnt = eoff[e + 1] - beg;
  const int h0 = ht * 64;

  __shared__ unsigned short sA[128 * 64];
  __shared__ unsigned short sB[64 * 64];

  const int tid = threadIdx.x;
  const int ar = tid >> 1, ac = (tid & 1) * 32;
  const int br = tid >> 2, bc = (tid & 3) * 16;

  const bool av = (m0 + ar) < cnt;
  const unsigned short* arow = act + (size_t)(beg + (av ? m0 + ar : 0)) * I + ac;
  const float* brow = w2 + ((size_t)e * H + h0 + br) * I + bc;

  const int lane = tid & 63, wid = tid >> 6;
  const int wm = wid << 5;
  const int fr = lane & 15, fq = lane >> 4;

  f32x4 acc[2][4];
#pragma unroll
  for (int a = 0; a < 2; ++a)
#pragma unroll
    for (int b = 0; b < 4; ++b) acc[a][b] = {0.f, 0.f, 0.f, 0.f};

  bf16x8 ra[4];
  f32x4 rb[4];

  auto LOAD = [&](int kk) {
#pragma unroll
    for (int s = 0; s < 4; ++s) {
      ra[s] = *reinterpret_cast<const bf16x8*>(arow + kk + s * 8);
      rb[s] = *reinterpret_cast<const f32x4*>(brow + kk + s * 4);
    }
  };

  constexpr int NT = I / 64;
  LOAD(0);
  for (int t = 0; t < NT; ++t) {
    const bf16x8 wb0 = pack8(rb[0], rb[1]), wb1 = pack8(rb[2], rb[3]);
    __syncthreads();
    st8(sA, ar, ac + 0, ra[0]); st8(sA, ar, ac + 8, ra[1]);
    st8(sA, ar, ac + 16, ra[2]); st8(sA, ar, ac + 24, ra[3]);
    st8(sB, br, bc, wb0); st8(sB, br, bc + 8, wb1);
    if (t + 1 < NT) LOAD((t + 1) * 64);
    __syncthreads();
#pragma unroll
    for (int kb = 0; kb < 2; ++kb) {
      const int k8 = (kb << 5) + (fq << 3);
      bf16x8 af[2], bf[4];
#pragma unroll
      for (int mi = 0; mi < 2; ++mi) af[mi] = ld8(sA, wm + (mi << 4) + fr, k8);
#pragma unroll
      for (int nj = 0; nj < 4; ++nj) bf[nj] = ld8(sB, (nj << 4) + fr, k8);
#pragma unroll
      for (int mi = 0; mi < 2; ++mi)
#pragma unroll
        for (int nj = 0; nj < 4; ++nj)
          acc[mi][nj] = __builtin_amdgcn_mfma_f32_16x16x32_bf16(af[mi], bf[nj], acc[mi][nj], 0, 0, 0);
    }
  }

#pragma unroll
  for (int mi = 0; mi < 2; ++mi)
#pragma unroll
    for (int q = 0; q < 4; ++q) {
      const int m = m0 + wm + (mi << 4) + (fq << 2) + q;
      if (m >= cnt) continue;
      const int tt = pair_t[beg + m];
      const float w = pair_w[beg + m];
#pragma unroll
      for (int nj = 0; nj < 4; ++nj)
        atomicAdd(out + (size_t)tt * H + h0 + (nj << 4) + fr, w * acc[mi][nj][q]);
    }
}

// ---------------------------------------------------------------------------
// LoRA delta (fp32): out[t] += sc * (x[t]·A^T masked) · B^T
// ---------------------------------------------------------------------------
__global__ __launch_bounds__(256) void lora_kernel(
    const float* __restrict__ x, const float* __restrict__ lora_a,
    const float* __restrict__ lora_b, const int* __restrict__ lora_idx,
    const int* __restrict__ lora_ranks, const float* __restrict__ scalings,
    const int* __restrict__ pair_t, const int* __restrict__ pair_e,
    float* __restrict__ out) {
  const int p = blockIdx.x;
  const int t = pair_t[p];
  const int e = pair_e[p];
  const int l = lora_idx[t];
  if (l < 0) return;
  int rank = lora_ranks[l];
  if (rank < 1) rank = 1;
  const float sc = scalings[l];

  __shared__ float a_sh[R];
  const int tid = threadIdx.x;
  const int wave = tid >> 6, lane = tid & 63;
  const float4* xv = reinterpret_cast<const float4*>(x + (size_t)t * H);
  const float* Ab = lora_a + (size_t)(l * E + e) * R * H;
#pragma unroll
  for (int q = 0; q < 4; ++q) {
    const int r = (wave << 2) | q;
    const float4* Av = reinterpret_cast<const float4*>(Ab + (size_t)r * H);
    float s = 0.f;
#pragma unroll
    for (int it = 0; it < H / 256; ++it) {
      const int h4 = it * 64 + lane;
      const float4 xx = xv[h4];
      const float4 aa = Av[h4];
      s += xx.x * aa.x + xx.y * aa.y + xx.z * aa.z + xx.w * aa.w;
    }
#pragma unroll
    for (int off = 32; off; off >>= 1) s += __shfl_xor(s, off);
    if (lane == 0) a_sh[r] = (r < rank) ? s * sc : 0.f;
  }
  __syncthreads();
  const float* Bb = lora_b + (size_t)(l * E + e) * H * R;
  for (int h = tid; h < H; h += 256) {
    const float4* Bv = reinterpret_cast<const float4*>(Bb + (size_t)h * R);
    float d = 0.f;
#pragma unroll
    for (int r4 = 0; r4 < 4; ++r4) {
      const float4 bb = Bv[r4];
      d += a_sh[r4 * 4 + 0] * bb.x + a_sh[r4 * 4 + 1] * bb.y +
           a_sh[r4 * 4 + 2] * bb.z + a_sh[r4 * 4 + 3] * bb.w;
    }
    atomicAdd(out + (size_t)t * H + h, d);
  }
}

extern "C" void kernel_launch(void* const* d_in, const int* in_sizes, int n_in,
                              void* d_out, int out_size, void* d_ws, size_t ws_size,
                              hipStream_t stream) {
  const float* x          = (const float*)d_in[0];
  const int*   topk_ids   = (const int*)d_in[1];
  const float* topk_w     = (const float*)d_in[2];
  const int*   lora_idx   = (const int*)d_in[3];
  const int*   lora_ranks = (const int*)d_in[4];
  const float* scalings   = (const float*)d_in[5];
  const float* w1         = (const float*)d_in[6];
  const float* w2         = (const float*)d_in[7];
  const float* lora_a     = (const float*)d_in[8];
  const float* lora_b     = (const float*)d_in[9];
  float* out = (float*)d_out;

  char* ws = (char*)d_ws;
  int*   eoff    = (int*)(ws);             // 17 ints
  int*   ntiles  = (int*)(ws + 96);        // 1 int
  int*   tile_e  = (int*)(ws + 256);       // 32 ints
  int*   tile_m0 = (int*)(ws + 384);       // 32 ints
  int*   pair_t  = (int*)(ws + 512);
  int*   pair_e  = (int*)(ws + 512 + 4 * P);
  float* pair_w  = (float*)(ws + 512 + 8 * P);
  unsigned short* xb  = (unsigned short*)(ws + 32768);                      // T*H bf16 = 4MB
  unsigned short* act = (unsigned short*)(ws + 32768 + (size_t)T * H * 2);  // P*I bf16 = 4MB

  hipMemsetAsync(d_out, 0, (size_t)T * H * sizeof(float), stream);

  xcvt<<<T * H / (256 * 8), 256, 0, stream>>>(x, xb);
  route_kernel<<<1, 256, 0, stream>>>(topk_ids, topk_w, eoff, pair_t, pair_w, pair_e,
                                      tile_e, tile_m0, ntiles);
  gemm1_mfma<<<MT_MAX * 16, 256, 0, stream>>>(xb, w1, eoff, pair_t, tile_e, tile_m0,
                                              ntiles, act);
  gemm2_mfma<<<MT_MAX * 32, 256, 0, stream>>>(act, w2, eoff, pair_t, pair_w, tile_e,
                                              tile_m0, ntiles, out);
  lora_kernel<<<P, 256, 0, stream>>>(x, lora_a, lora_b, lora_idx, lora_ranks, scalings,
                                     pair_t, pair_e, out);
}

// Round 5
// 208.215 us; speedup vs baseline: 17.6494x; 1.0087x over previous
//
#include <hip/hip_runtime.h>
#include <math.h>

constexpr int T = 1024;
constexpr int H = 2048;
constexpr int I = 1024;
constexpr int E = 16;
constexpr int K = 2;
constexpr int L = 4;
constexpr int R = 16;
constexpr int P = T * K;        // 2048 (token,k) pairs
constexpr int MT_MAX = 32;      // max m-tiles (BM=128)

typedef __attribute__((ext_vector_type(8))) short bf16x8;
typedef __attribute__((ext_vector_type(4))) float f32x4;

__device__ inline unsigned short f2bf(float f) {
  unsigned u = __builtin_bit_cast(unsigned, f);
  u = (u + 0x7FFFu + ((u >> 16) & 1u)) >> 16;
  return (unsigned short)u;
}

__device__ inline bf16x8 pack8(f32x4 a, f32x4 b) {
  bf16x8 v;
  v[0] = (short)f2bf(a[0]); v[1] = (short)f2bf(a[1]);
  v[2] = (short)f2bf(a[2]); v[3] = (short)f2bf(a[3]);
  v[4] = (short)f2bf(b[0]); v[5] = (short)f2bf(b[1]);
  v[6] = (short)f2bf(b[2]); v[7] = (short)f2bf(b[3]);
  return v;
}

// LDS tile, 64 bf16 cols per row (128B rows); XOR swizzle (0 conflicts, verified)
__device__ inline void st8(unsigned short* s, int r, int c, bf16x8 v) {
  int byte = ((r << 6) + c) * 2;
  byte ^= (r & 7) << 4;
  *reinterpret_cast<bf16x8*>(reinterpret_cast<char*>(s) + byte) = v;
}
__device__ inline bf16x8 ld8(const unsigned short* s, int r, int c) {
  int byte = ((r << 6) + c) * 2;
  byte ^= (r & 7) << 4;
  return *reinterpret_cast<const bf16x8*>(reinterpret_cast<const char*>(s) + byte);
}

// ---------------------------------------------------------------------------
// routing: sort (token,k) pairs by expert + emit compact m-tile table
// ---------------------------------------------------------------------------
__global__ __launch_bounds__(256) void route_kernel(
    const int* __restrict__ topk_ids, const float* __restrict__ topk_w,
    int* __restrict__ eoff, int* __restrict__ pair_t,
    float* __restrict__ pair_w, int* __restrict__ pair_e,
    int* __restrict__ tile_e, int* __restrict__ tile_m0, int* __restrict__ ntiles) {
  __shared__ int cnt[E];
  __shared__ int off[E + 1];
  __shared__ int cur[E];
  const int tid = threadIdx.x;
  if (tid < E) cnt[tid] = 0;
  __syncthreads();
  for (int p = tid; p < P; p += blockDim.x) atomicAdd(&cnt[topk_ids[p]], 1);
  __syncthreads();
  if (tid == 0) {
    off[0] = 0;
    for (int e = 0; e < E; ++e) off[e + 1] = off[e] + cnt[e];
    int nt = 0;
    for (int e = 0; e < E; ++e)
      for (int m0 = 0; m0 < cnt[e]; m0 += 128) {
        tile_e[nt] = e;
        tile_m0[nt] = m0;
        ++nt;
      }
    *ntiles = nt;
  }
  __syncthreads();
  if (tid < E) cur[tid] = off[tid];
  if (tid <= E) eoff[tid] = off[tid];
  __syncthreads();
  for (int p = tid; p < P; p += blockDim.x) {
    const int e = topk_ids[p];
    const int pos = atomicAdd(&cur[e], 1);
    pair_t[pos] = p / K;
    pair_w[pos] = topk_w[p];
    pair_e[pos] = e;
  }
}

// x (fp32) -> xb (bf16) AND zero out[] (replaces slow runtime memset)
__global__ __launch_bounds__(256) void xcvt_zero(const float* __restrict__ x,
                                                unsigned short* __restrict__ xb,
                                                float* __restrict__ out) {
  const int i = (blockIdx.x * 256 + threadIdx.x) * 8;
  f32x4 a = *reinterpret_cast<const f32x4*>(x + i);
  f32x4 b = *reinterpret_cast<const f32x4*>(x + i + 4);
  *reinterpret_cast<bf16x8*>(xb + i) = pack8(a, b);
  const f32x4 z = {0.f, 0.f, 0.f, 0.f};
  *reinterpret_cast<f32x4*>(out + i) = z;
  *reinterpret_cast<f32x4*>(out + i + 4) = z;
}

// ---------------------------------------------------------------------------
// GEMM1: act[p,i] = silu(x·w1_gate)*(x·w1_up).  BM=128 x BN=64 x BK=64.
// 1-D compact grid: bid = mt*16 + it  (all blocks are real work)
// ---------------------------------------------------------------------------
__global__ __launch_bounds__(256) void gemm1_mfma(
    const unsigned short* __restrict__ xb, const float* __restrict__ w1,
    const int* __restrict__ eoff, const int* __restrict__ pair_t,
    const int* __restrict__ tile_e, const int* __restrict__ tile_m0,
    const int* __restrict__ ntiles, unsigned short* __restrict__ act) {
  const int bid = blockIdx.x;
  const int mt = bid >> 4;
  if (mt >= *ntiles) return;
  const int it = bid & 15;
  const int e = tile_e[mt];
  const int m0 = tile_m0[mt];
  const int beg = eoff[e];
  const int cnt = eoff[e + 1] - beg;
  const int i0 = it * 64;

  __shared__ unsigned short sX[128 * 64];
  __shared__ unsigned short sG[64 * 64];
  __shared__ unsigned short sU[64 * 64];

  const int tid = threadIdx.x;
  const int xr = tid >> 1, xc = (tid & 1) * 32;
  const int gr = tid >> 2, gc = (tid & 3) * 16;

  const int rm = m0 + xr;
  const int tok = (rm < cnt) ? pair_t[beg + rm] : -1;
  const unsigned short* xrow = xb + (size_t)(tok < 0 ? 0 : tok) * H + xc;
  const float* grow = w1 + ((size_t)e * (2 * I) + i0 + gr) * H + gc;
  const float* urow = grow + (size_t)I * H;

  const int lane = tid & 63, wid = tid >> 6;
  const int wm = wid << 5;
  const int fr = lane & 15, fq = lane >> 4;

  f32x4 ag[2][4], au[2][4];
#pragma unroll
  for (int a = 0; a < 2; ++a)
#pragma unroll
    for (int b = 0; b < 4; ++b) {
      ag[a][b] = {0.f, 0.f, 0.f, 0.f};
      au[a][b] = {0.f, 0.f, 0.f, 0.f};
    }

  bf16x8 rx[4];
  f32x4 rg[4], ru[4];
  const bf16x8 zero8 = {0, 0, 0, 0, 0, 0, 0, 0};

  auto LOAD = [&](int kk) {
    if (tok >= 0) {
#pragma unroll
      for (int s = 0; s < 4; ++s)
        rx[s] = *reinterpret_cast<const bf16x8*>(xrow + kk + s * 8);
    } else {
#pragma unroll
      for (int s = 0; s < 4; ++s) rx[s] = zero8;
    }
#pragma unroll
    for (int s = 0; s < 4; ++s) {
      rg[s] = *reinterpret_cast<const f32x4*>(grow + kk + s * 4);
      ru[s] = *reinterpret_cast<const f32x4*>(urow + kk + s * 4);
    }
  };

  constexpr int NT = H / 64;
  LOAD(0);
  for (int t = 0; t < NT; ++t) {
    const bf16x8 wg0 = pack8(rg[0], rg[1]), wg1 = pack8(rg[2], rg[3]);
    const bf16x8 wu0 = pack8(ru[0], ru[1]), wu1 = pack8(ru[2], ru[3]);
    __syncthreads();
    st8(sX, xr, xc + 0, rx[0]); st8(sX, xr, xc + 8, rx[1]);
    st8(sX, xr, xc + 16, rx[2]); st8(sX, xr, xc + 24, rx[3]);
    st8(sG, gr, gc, wg0); st8(sG, gr, gc + 8, wg1);
    st8(sU, gr, gc, wu0); st8(sU, gr, gc + 8, wu1);
    if (t + 1 < NT) LOAD((t + 1) * 64);
    __syncthreads();
#pragma unroll
    for (int kb = 0; kb < 2; ++kb) {
      const int k8 = (kb << 5) + (fq << 3);
      bf16x8 af[2], gf[4], uf[4];
#pragma unroll
      for (int mi = 0; mi < 2; ++mi) af[mi] = ld8(sX, wm + (mi << 4) + fr, k8);
#pragma unroll
      for (int nj = 0; nj < 4; ++nj) {
        gf[nj] = ld8(sG, (nj << 4) + fr, k8);
        uf[nj] = ld8(sU, (nj << 4) + fr, k8);
      }
#pragma unroll
      for (int mi = 0; mi < 2; ++mi)
#pragma unroll
        for (int nj = 0; nj < 4; ++nj) {
          ag[mi][nj] = __builtin_amdgcn_mfma_f32_16x16x32_bf16(af[mi], gf[nj], ag[mi][nj], 0, 0, 0);
          au[mi][nj] = __builtin_amdgcn_mfma_f32_16x16x32_bf16(af[mi], uf[nj], au[mi][nj], 0, 0, 0);
        }
    }
  }

#pragma unroll
  for (int mi = 0; mi < 2; ++mi)
#pragma unroll
    for (int q = 0; q < 4; ++q) {
      const int m = m0 + wm + (mi << 4) + (fq << 2) + q;
      if (m >= cnt) continue;
#pragma unroll
      for (int nj = 0; nj < 4; ++nj) {
        const float g = ag[mi][nj][q];
        const float u = au[mi][nj][q];
        const float s = g / (1.f + __expf(-g));
        act[(size_t)(beg + m) * I + i0 + (nj << 4) + fr] = f2bf(s * u);
      }
    }
}

// ---------------------------------------------------------------------------
// GEMM2: out[t,h] += pw * (act[p,:]·w2[e,h,:]).  BM=128 x BN=64 x BK=64.
// 1-D compact grid: bid = mt*32 + ht
// ---------------------------------------------------------------------------
__global__ __launch_bounds__(256) void gemm2_mfma(
    const unsigned short* __restrict__ act, const float* __restrict__ w2,
    const int* __restrict__ eoff, const int* __restrict__ pair_t,
    const float* __restrict__ pair_w, const int* __restrict__ tile_e,
    const int* __restrict__ tile_m0, const int* __restrict__ ntiles,
    float* __restrict__ out) {
  const int bid = blockIdx.x;
  const int mt = bid >> 5;
  if (mt >= *ntiles) return;
  const int ht = bid & 31;
  const int e = tile_e[mt];
  const int m0 = tile_m0[mt];
  const int beg = eoff[e];
  const int cnt = eoff[e + 1] - beg;
  const int h0 = ht * 64;

  __shared__ unsigned short sA[128 * 64];
  __shared__ unsigned short sB[64 * 64];

  const int tid = threadIdx.x;
  const int ar = tid >> 1, ac = (tid & 1) * 32;
  const int br = tid >> 2, bc = (tid & 3) * 16;

  const bool av = (m0 + ar) < cnt;
  const unsigned short* arow = act + (size_t)(beg + (av ? m0 + ar : 0)) * I + ac;
  const float* brow = w2 + ((size_t)e * H + h0 + br) * I + bc;

  const int lane = tid & 63, wid = tid >> 6;
  const int wm = wid << 5;
  const int fr = lane & 15, fq = lane >> 4;

  f32x4 acc[2][4];
#pragma unroll
  for (int a = 0; a < 2; ++a)
#pragma unroll
    for (int b = 0; b < 4; ++b) acc[a][b] = {0.f, 0.f, 0.f, 0.f};

  bf16x8 ra[4];
  f32x4 rb[4];

  auto LOAD = [&](int kk) {
#pragma unroll
    for (int s = 0; s < 4; ++s) {
      ra[s] = *reinterpret_cast<const bf16x8*>(arow + kk + s * 8);
      rb[s] = *reinterpret_cast<const f32x4*>(brow + kk + s * 4);
    }
  };

  constexpr int NT = I / 64;
  LOAD(0);
  for (int t = 0; t < NT; ++t) {
    const bf16x8 wb0 = pack8(rb[0], rb[1]), wb1 = pack8(rb[2], rb[3]);
    __syncthreads();
    st8(sA, ar, ac + 0, ra[0]); st8(sA, ar, ac + 8, ra[1]);
    st8(sA, ar, ac + 16, ra[2]); st8(sA, ar, ac + 24, ra[3]);
    st8(sB, br, bc, wb0); st8(sB, br, bc + 8, wb1);
    if (t + 1 < NT) LOAD((t + 1) * 64);
    __syncthreads();
#pragma unroll
    for (int kb = 0; kb < 2; ++kb) {
      const int k8 = (kb << 5) + (fq << 3);
      bf16x8 af[2], bf[4];
#pragma unroll
      for (int mi = 0; mi < 2; ++mi) af[mi] = ld8(sA, wm + (mi << 4) + fr, k8);
#pragma unroll
      for (int nj = 0; nj < 4; ++nj) bf[nj] = ld8(sB, (nj << 4) + fr, k8);
#pragma unroll
      for (int mi = 0; mi < 2; ++mi)
#pragma unroll
        for (int nj = 0; nj < 4; ++nj)
          acc[mi][nj] = __builtin_amdgcn_mfma_f32_16x16x32_bf16(af[mi], bf[nj], acc[mi][nj], 0, 0, 0);
    }
  }

#pragma unroll
  for (int mi = 0; mi < 2; ++mi)
#pragma unroll
    for (int q = 0; q < 4; ++q) {
      const int m = m0 + wm + (mi << 4) + (fq << 2) + q;
      if (m >= cnt) continue;
      const int tt = pair_t[beg + m];
      const float w = pair_w[beg + m];
#pragma unroll
      for (int nj = 0; nj < 4; ++nj)
        atomicAdd(out + (size_t)tt * H + h0 + (nj << 4) + fr, w * acc[mi][nj][q]);
    }
}

// ---------------------------------------------------------------------------
// LoRA delta (fp32): out[t] += sc * (x[t]·A^T masked) · B^T
// ---------------------------------------------------------------------------
__global__ __launch_bounds__(256) void lora_kernel(
    const float* __restrict__ x, const float* __restrict__ lora_a,
    const float* __restrict__ lora_b, const int* __restrict__ lora_idx,
    const int* __restrict__ lora_ranks, const float* __restrict__ scalings,
    const int* __restrict__ pair_t, const int* __restrict__ pair_e,
    float* __restrict__ out) {
  const int p = blockIdx.x;
  const int t = pair_t[p];
  const int e = pair_e[p];
  const int l = lora_idx[t];
  if (l < 0) return;
  int rank = lora_ranks[l];
  if (rank < 1) rank = 1;
  const float sc = scalings[l];

  __shared__ float a_sh[R];
  const int tid = threadIdx.x;
  const int wave = tid >> 6, lane = tid & 63;
  const float4* xv = reinterpret_cast<const float4*>(x + (size_t)t * H);
  const float* Ab = lora_a + (size_t)(l * E + e) * R * H;
#pragma unroll
  for (int q = 0; q < 4; ++q) {
    const int r = (wave << 2) | q;
    const float4* Av = reinterpret_cast<const float4*>(Ab + (size_t)r * H);
    float s = 0.f;
#pragma unroll
    for (int it = 0; it < H / 256; ++it) {
      const int h4 = it * 64 + lane;
      const float4 xx = xv[h4];
      const float4 aa = Av[h4];
      s += xx.x * aa.x + xx.y * aa.y + xx.z * aa.z + xx.w * aa.w;
    }
#pragma unroll
    for (int off = 32; off; off >>= 1) s += __shfl_xor(s, off);
    if (lane == 0) a_sh[r] = (r < rank) ? s * sc : 0.f;
  }
  __syncthreads();
  const float* Bb = lora_b + (size_t)(l * E + e) * H * R;
  for (int h = tid; h < H; h += 256) {
    const float4* Bv = reinterpret_cast<const float4*>(Bb + (size_t)h * R);
    float d = 0.f;
#pragma unroll
    for (int r4 = 0; r4 < 4; ++r4) {
      const float4 bb = Bv[r4];
      d += a_sh[r4 * 4 + 0] * bb.x + a_sh[r4 * 4 + 1] * bb.y +
           a_sh[r4 * 4 + 2] * bb.z + a_sh[r4 * 4 + 3] * bb.w;
    }
    atomicAdd(out + (size_t)t * H + h, d);
  }
}

extern "C" void kernel_launch(void* const* d_in, const int* in_sizes, int n_in,
                              void* d_out, int out_size, void* d_ws, size_t ws_size,
                              hipStream_t stream) {
  const float* x          = (const float*)d_in[0];
  const int*   topk_ids   = (const int*)d_in[1];
  const float* topk_w     = (const float*)d_in[2];
  const int*   lora_idx   = (const int*)d_in[3];
  const int*   lora_ranks = (const int*)d_in[4];
  const float* scalings   = (const float*)d_in[5];
  const float* w1         = (const float*)d_in[6];
  const float* w2         = (const float*)d_in[7];
  const float* lora_a     = (const float*)d_in[8];
  const float* lora_b     = (const float*)d_in[9];
  float* out = (float*)d_out;

  char* ws = (char*)d_ws;
  int*   eoff    = (int*)(ws);             // 17 ints
  int*   ntiles  = (int*)(ws + 96);        // 1 int
  int*   tile_e  = (int*)(ws + 256);       // 32 ints
  int*   tile_m0 = (int*)(ws + 384);       // 32 ints
  int*   pair_t  = (int*)(ws + 512);
  int*   pair_e  = (int*)(ws + 512 + 4 * P);
  float* pair_w  = (float*)(ws + 512 + 8 * P);
  unsigned short* xb  = (unsigned short*)(ws + 32768);                      // T*H bf16 = 4MB
  unsigned short* act = (unsigned short*)(ws + 32768 + (size_t)T * H * 2);  // P*I bf16 = 4MB

  xcvt_zero<<<T * H / (256 * 8), 256, 0, stream>>>(x, xb, out);
  route_kernel<<<1, 256, 0, stream>>>(topk_ids, topk_w, eoff, pair_t, pair_w, pair_e,
                                      tile_e, tile_m0, ntiles);
  gemm1_mfma<<<MT_MAX * 16, 256, 0, stream>>>(xb, w1, eoff, pair_t, tile_e, tile_m0,
                                              ntiles, act);
  gemm2_mfma<<<MT_MAX * 32, 256, 0, stream>>>(act, w2, eoff, pair_t, pair_w, tile_e,
                                              tile_m0, ntiles, out);
  lora_kernel<<<P, 256, 0, stream>>>(x, lora_a, lora_b, lora_idx, lora_ranks, scalings,
                                     pair_t, pair_e, out);
}

// Round 6
// 177.172 us; speedup vs baseline: 20.7419x; 1.1752x over previous
//
#include <hip/hip_runtime.h>
#include <math.h>

constexpr int T = 1024;
constexpr int H = 2048;
constexpr int I = 1024;
constexpr int E = 16;
constexpr int K = 2;
constexpr int L = 4;
constexpr int R = 16;
constexpr int P = T * K;        // 2048 (token,k) pairs
constexpr int MT_MAX = 32;      // max m-tiles (BM=128)
constexpr int G_CVT = T * H / (256 * 8);   // 1024 convert blocks
constexpr int G1 = MT_MAX * 32;            // 1024 gemm1 block ids (BN=32)
constexpr int G2 = MT_MAX * 64;            // 2048 gemm2 block ids (BN=32)

typedef __attribute__((ext_vector_type(8))) short bf16x8;
typedef __attribute__((ext_vector_type(4))) float f32x4;

__device__ inline unsigned short f2bf(float f) {
  unsigned u = __builtin_bit_cast(unsigned, f);
  u = (u + 0x7FFFu + ((u >> 16) & 1u)) >> 16;
  return (unsigned short)u;
}

__device__ inline bf16x8 pack8(f32x4 a, f32x4 b) {
  bf16x8 v;
  v[0] = (short)f2bf(a[0]); v[1] = (short)f2bf(a[1]);
  v[2] = (short)f2bf(a[2]); v[3] = (short)f2bf(a[3]);
  v[4] = (short)f2bf(b[0]); v[5] = (short)f2bf(b[1]);
  v[6] = (short)f2bf(b[2]); v[7] = (short)f2bf(b[3]);
  return v;
}

// LDS tile rows of 64 bf16 (128B); XOR swizzle (0 conflicts, verified r2-r5)
__device__ inline void st8(unsigned short* s, int r, int c, bf16x8 v) {
  int byte = ((r << 6) + c) * 2;
  byte ^= (r & 7) << 4;
  *reinterpret_cast<bf16x8*>(reinterpret_cast<char*>(s) + byte) = v;
}
__device__ inline bf16x8 ld8(const unsigned short* s, int r, int c) {
  int byte = ((r << 6) + c) * 2;
  byte ^= (r & 7) << 4;
  return *reinterpret_cast<const bf16x8*>(reinterpret_cast<const char*>(s) + byte);
}

// ---------------------------------------------------------------------------
// Launch 1: x->bf16 convert + out zero (blocks 0..1023)  ||  routing (block 1024)
// ---------------------------------------------------------------------------
__global__ __launch_bounds__(256) void prep_kernel(
    const float* __restrict__ x, unsigned short* __restrict__ xb,
    float* __restrict__ out,
    const int* __restrict__ topk_ids, const float* __restrict__ topk_w,
    int* __restrict__ eoff, int* __restrict__ pair_t,
    float* __restrict__ pair_w, int* __restrict__ pair_e,
    int* __restrict__ tile_e, int* __restrict__ tile_m0, int* __restrict__ ntiles) {
  const int tid = threadIdx.x;
  if (blockIdx.x < G_CVT) {
    const int i = (blockIdx.x * 256 + tid) * 8;
    f32x4 a = *reinterpret_cast<const f32x4*>(x + i);
    f32x4 b = *reinterpret_cast<const f32x4*>(x + i + 4);
    *reinterpret_cast<bf16x8*>(xb + i) = pack8(a, b);
    const f32x4 z = {0.f, 0.f, 0.f, 0.f};
    *reinterpret_cast<f32x4*>(out + i) = z;
    *reinterpret_cast<f32x4*>(out + i + 4) = z;
    return;
  }
  // routing block
  __shared__ int cnt[E];
  __shared__ int off[E + 1];
  __shared__ int cur[E];
  if (tid < E) cnt[tid] = 0;
  __syncthreads();
  for (int p = tid; p < P; p += 256) atomicAdd(&cnt[topk_ids[p]], 1);
  __syncthreads();
  if (tid == 0) {
    off[0] = 0;
    for (int e = 0; e < E; ++e) off[e + 1] = off[e] + cnt[e];
    int nt = 0;
    for (int e = 0; e < E; ++e)
      for (int m0 = 0; m0 < cnt[e]; m0 += 128) {
        tile_e[nt] = e;
        tile_m0[nt] = m0;
        ++nt;
      }
    *ntiles = nt;
  }
  __syncthreads();
  if (tid < E) cur[tid] = off[tid];
  if (tid <= E) eoff[tid] = off[tid];
  __syncthreads();
  for (int p = tid; p < P; p += 256) {
    const int e = topk_ids[p];
    const int pos = atomicAdd(&cur[e], 1);
    pair_t[pos] = p / K;
    pair_w[pos] = topk_w[p];
    pair_e[pos] = e;
  }
}

// ---------------------------------------------------------------------------
// Launch 2: gemm1 (blocks 0..G1-1, BM=128 x BN=32 x BK=64)  ||  lora (G1..G1+P-1)
// ---------------------------------------------------------------------------
__global__ __launch_bounds__(256) void gemm1_lora(
    const unsigned short* __restrict__ xb, const float* __restrict__ w1,
    const int* __restrict__ eoff, const int* __restrict__ pair_t,
    const int* __restrict__ tile_e, const int* __restrict__ tile_m0,
    const int* __restrict__ ntiles, unsigned short* __restrict__ act,
    const float* __restrict__ x, const float* __restrict__ lora_a,
    const float* __restrict__ lora_b, const int* __restrict__ lora_idx,
    const int* __restrict__ lora_ranks, const float* __restrict__ scalings,
    const int* __restrict__ pair_e, float* __restrict__ out) {
  __shared__ __align__(16) char smem[24576];
  const int tid = threadIdx.x;

  if (blockIdx.x < (unsigned)G1) {
    // ---------------- gemm1 path ----------------
    const int bid = blockIdx.x;
    const int mt = bid >> 5;
    if (mt >= *ntiles) return;
    const int it = bid & 31;
    const int e = tile_e[mt];
    const int m0 = tile_m0[mt];
    const int beg = eoff[e];
    const int cnt = eoff[e + 1] - beg;
    const int i0 = it * 32;

    unsigned short* sX = (unsigned short*)smem;            // 128x64 = 16KB
    unsigned short* sG = (unsigned short*)(smem + 16384);  // 32x64  = 4KB
    unsigned short* sU = (unsigned short*)(smem + 20480);  // 32x64  = 4KB

    const int xr = tid >> 1, xc = (tid & 1) * 32;
    const int gr = tid >> 3, gc = (tid & 7) * 8;

    const int rm = m0 + xr;
    const int tok = (rm < cnt) ? pair_t[beg + rm] : -1;
    const unsigned short* xrow = xb + (size_t)(tok < 0 ? 0 : tok) * H + xc;
    const float* grow = w1 + ((size_t)e * (2 * I) + i0 + gr) * H + gc;
    const float* urow = grow + (size_t)I * H;

    const int lane = tid & 63, wid = tid >> 6;
    const int wm = wid << 5;
    const int fr = lane & 15, fq = lane >> 4;

    f32x4 ag[2][2], au[2][2];
#pragma unroll
    for (int a = 0; a < 2; ++a)
#pragma unroll
      for (int b = 0; b < 2; ++b) {
        ag[a][b] = {0.f, 0.f, 0.f, 0.f};
        au[a][b] = {0.f, 0.f, 0.f, 0.f};
      }

    bf16x8 rx[4];
    f32x4 rg[2], ru[2];
    const bf16x8 zero8 = {0, 0, 0, 0, 0, 0, 0, 0};

    auto LOAD = [&](int kk) {
      if (tok >= 0) {
#pragma unroll
        for (int s = 0; s < 4; ++s)
          rx[s] = *reinterpret_cast<const bf16x8*>(xrow + kk + s * 8);
      } else {
#pragma unroll
        for (int s = 0; s < 4; ++s) rx[s] = zero8;
      }
#pragma unroll
      for (int s = 0; s < 2; ++s) {
        rg[s] = *reinterpret_cast<const f32x4*>(grow + kk + s * 4);
        ru[s] = *reinterpret_cast<const f32x4*>(urow + kk + s * 4);
      }
    };

    constexpr int NT = H / 64;
    LOAD(0);
    for (int t = 0; t < NT; ++t) {
      const bf16x8 wg = pack8(rg[0], rg[1]);
      const bf16x8 wu = pack8(ru[0], ru[1]);
      __syncthreads();
      st8(sX, xr, xc + 0, rx[0]); st8(sX, xr, xc + 8, rx[1]);
      st8(sX, xr, xc + 16, rx[2]); st8(sX, xr, xc + 24, rx[3]);
      st8(sG, gr, gc, wg);
      st8(sU, gr, gc, wu);
      if (t + 1 < NT) LOAD((t + 1) * 64);
      __syncthreads();
#pragma unroll
      for (int kb = 0; kb < 2; ++kb) {
        const int k8 = (kb << 5) + (fq << 3);
        bf16x8 af[2], gf[2], uf[2];
#pragma unroll
        for (int mi = 0; mi < 2; ++mi) af[mi] = ld8(sX, wm + (mi << 4) + fr, k8);
#pragma unroll
        for (int nj = 0; nj < 2; ++nj) {
          gf[nj] = ld8(sG, (nj << 4) + fr, k8);
          uf[nj] = ld8(sU, (nj << 4) + fr, k8);
        }
#pragma unroll
        for (int mi = 0; mi < 2; ++mi)
#pragma unroll
          for (int nj = 0; nj < 2; ++nj) {
            ag[mi][nj] = __builtin_amdgcn_mfma_f32_16x16x32_bf16(af[mi], gf[nj], ag[mi][nj], 0, 0, 0);
            au[mi][nj] = __builtin_amdgcn_mfma_f32_16x16x32_bf16(af[mi], uf[nj], au[mi][nj], 0, 0, 0);
          }
      }
    }

#pragma unroll
    for (int mi = 0; mi < 2; ++mi)
#pragma unroll
      for (int q = 0; q < 4; ++q) {
        const int m = m0 + wm + (mi << 4) + (fq << 2) + q;
        if (m >= cnt) continue;
#pragma unroll
        for (int nj = 0; nj < 2; ++nj) {
          const float g = ag[mi][nj][q];
          const float u = au[mi][nj][q];
          const float s = g / (1.f + __expf(-g));
          act[(size_t)(beg + m) * I + i0 + (nj << 4) + fr] = f2bf(s * u);
        }
      }
    return;
  }

  // ---------------- lora path ----------------
  const int p = blockIdx.x - G1;
  const int t = pair_t[p];
  const int e = pair_e[p];
  const int l = lora_idx[t];
  if (l < 0) return;
  int rank = lora_ranks[l];
  if (rank < 1) rank = 1;
  const float sc = scalings[l];

  float* a_sh = (float*)smem;
  const int wave = tid >> 6, lane = tid & 63;
  const float4* xv = reinterpret_cast<const float4*>(x + (size_t)t * H);
  const float* Ab = lora_a + (size_t)(l * E + e) * R * H;
#pragma unroll
  for (int q = 0; q < 4; ++q) {
    const int r = (wave << 2) | q;
    const float4* Av = reinterpret_cast<const float4*>(Ab + (size_t)r * H);
    float s = 0.f;
#pragma unroll
    for (int it = 0; it < H / 256; ++it) {
      const int h4 = it * 64 + lane;
      const float4 xx = xv[h4];
      const float4 aa = Av[h4];
      s += xx.x * aa.x + xx.y * aa.y + xx.z * aa.z + xx.w * aa.w;
    }
#pragma unroll
    for (int off = 32; off; off >>= 1) s += __shfl_xor(s, off);
    if (lane == 0) a_sh[r] = (r < rank) ? s * sc : 0.f;
  }
  __syncthreads();
  const float* Bb = lora_b + (size_t)(l * E + e) * H * R;
  for (int h = tid; h < H; h += 256) {
    const float4* Bv = reinterpret_cast<const float4*>(Bb + (size_t)h * R);
    float d = 0.f;
#pragma unroll
    for (int r4 = 0; r4 < 4; ++r4) {
      const float4 bb = Bv[r4];
      d += a_sh[r4 * 4 + 0] * bb.x + a_sh[r4 * 4 + 1] * bb.y +
           a_sh[r4 * 4 + 2] * bb.z + a_sh[r4 * 4 + 3] * bb.w;
    }
    atomicAdd(out + (size_t)t * H + h, d);
  }
}

// ---------------------------------------------------------------------------
// Launch 3: GEMM2, BM=128 x BN=32 x BK=64; bid = mt*64 + ht
// ---------------------------------------------------------------------------
__global__ __launch_bounds__(256) void gemm2_mfma(
    const unsigned short* __restrict__ act, const float* __restrict__ w2,
    const int* __restrict__ eoff, const int* __restrict__ pair_t,
    const float* __restrict__ pair_w, const int* __restrict__ tile_e,
    const int* __restrict__ tile_m0, const int* __restrict__ ntiles,
    float* __restrict__ out) {
  const int bid = blockIdx.x;
  const int mt = bid >> 6;
  if (mt >= *ntiles) return;
  const int ht = bid & 63;
  const int e = tile_e[mt];
  const int m0 = tile_m0[mt];
  const int beg = eoff[e];
  const int cnt = eoff[e + 1] - beg;
  const int h0 = ht * 32;

  __shared__ unsigned short sA[128 * 64];
  __shared__ unsigned short sB[32 * 64];

  const int tid = threadIdx.x;
  const int ar = tid >> 1, ac = (tid & 1) * 32;
  const int br = tid >> 3, bc = (tid & 7) * 8;

  const bool av = (m0 + ar) < cnt;
  const unsigned short* arow = act + (size_t)(beg + (av ? m0 + ar : 0)) * I + ac;
  const float* brow = w2 + ((size_t)e * H + h0 + br) * I + bc;

  const int lane = tid & 63, wid = tid >> 6;
  const int wm = wid << 5;
  const int fr = lane & 15, fq = lane >> 4;

  f32x4 acc[2][2];
#pragma unroll
  for (int a = 0; a < 2; ++a)
#pragma unroll
    for (int b = 0; b < 2; ++b) acc[a][b] = {0.f, 0.f, 0.f, 0.f};

  bf16x8 ra[4];
  f32x4 rb[2];

  auto LOAD = [&](int kk) {
#pragma unroll
    for (int s = 0; s < 4; ++s)
      ra[s] = *reinterpret_cast<const bf16x8*>(arow + kk + s * 8);
#pragma unroll
    for (int s = 0; s < 2; ++s)
      rb[s] = *reinterpret_cast<const f32x4*>(brow + kk + s * 4);
  };

  constexpr int NT = I / 64;
  LOAD(0);
  for (int t = 0; t < NT; ++t) {
    const bf16x8 wb = pack8(rb[0], rb[1]);
    __syncthreads();
    st8(sA, ar, ac + 0, ra[0]); st8(sA, ar, ac + 8, ra[1]);
    st8(sA, ar, ac + 16, ra[2]); st8(sA, ar, ac + 24, ra[3]);
    st8(sB, br, bc, wb);
    if (t + 1 < NT) LOAD((t + 1) * 64);
    __syncthreads();
#pragma unroll
    for (int kb = 0; kb < 2; ++kb) {
      const int k8 = (kb << 5) + (fq << 3);
      bf16x8 af[2], bf[2];
#pragma unroll
      for (int mi = 0; mi < 2; ++mi) af[mi] = ld8(sA, wm + (mi << 4) + fr, k8);
#pragma unroll
      for (int nj = 0; nj < 2; ++nj) bf[nj] = ld8(sB, (nj << 4) + fr, k8);
#pragma unroll
      for (int mi = 0; mi < 2; ++mi)
#pragma unroll
        for (int nj = 0; nj < 2; ++nj)
          acc[mi][nj] = __builtin_amdgcn_mfma_f32_16x16x32_bf16(af[mi], bf[nj], acc[mi][nj], 0, 0, 0);
    }
  }

#pragma unroll
  for (int mi = 0; mi < 2; ++mi)
#pragma unroll
    for (int q = 0; q < 4; ++q) {
      const int m = m0 + wm + (mi << 4) + (fq << 2) + q;
      if (m >= cnt) continue;
      const int tt = pair_t[beg + m];
      const float w = pair_w[beg + m];
#pragma unroll
      for (int nj = 0; nj < 2; ++nj)
        atomicAdd(out + (size_t)tt * H + h0 + (nj << 4) + fr, w * acc[mi][nj][q]);
    }
}

extern "C" void kernel_launch(void* const* d_in, const int* in_sizes, int n_in,
                              void* d_out, int out_size, void* d_ws, size_t ws_size,
                              hipStream_t stream) {
  const float* x          = (const float*)d_in[0];
  const int*   topk_ids   = (const int*)d_in[1];
  const float* topk_w     = (const float*)d_in[2];
  const int*   lora_idx   = (const int*)d_in[3];
  const int*   lora_ranks = (const int*)d_in[4];
  const float* scalings   = (const float*)d_in[5];
  const float* w1         = (const float*)d_in[6];
  const float* w2         = (const float*)d_in[7];
  const float* lora_a     = (const float*)d_in[8];
  const float* lora_b     = (const float*)d_in[9];
  float* out = (float*)d_out;

  char* ws = (char*)d_ws;
  int*   eoff    = (int*)(ws);             // 17 ints
  int*   ntiles  = (int*)(ws + 96);        // 1 int
  int*   tile_e  = (int*)(ws + 256);       // 32 ints
  int*   tile_m0 = (int*)(ws + 384);       // 32 ints
  int*   pair_t  = (int*)(ws + 512);
  int*   pair_e  = (int*)(ws + 512 + 4 * P);
  float* pair_w  = (float*)(ws + 512 + 8 * P);
  unsigned short* xb  = (unsigned short*)(ws + 32768);                      // T*H bf16 = 4MB
  unsigned short* act = (unsigned short*)(ws + 32768 + (size_t)T * H * 2);  // P*I bf16 = 4MB

  prep_kernel<<<G_CVT + 1, 256, 0, stream>>>(x, xb, out, topk_ids, topk_w, eoff,
                                             pair_t, pair_w, pair_e, tile_e, tile_m0, ntiles);
  gemm1_lora<<<G1 + P, 256, 0, stream>>>(xb, w1, eoff, pair_t, tile_e, tile_m0, ntiles,
                                         act, x, lora_a, lora_b, lora_idx, lora_ranks,
                                         scalings, pair_e, out);
  gemm2_mfma<<<G2, 256, 0, stream>>>(act, w2, eoff, pair_t, pair_w, tile_e, tile_m0,
                                     ntiles, out);
}